// Round 13
// baseline (222.303 us; speedup 1.0000x reference)
//
#include <hip/hip_runtime.h>
#include <cmath>

#define LSEQ 2048
#define HID 512
#define NH 8
#define HD 64
#define QKVPN 3584
#define VPN 2560
#define TOK 4096

typedef _Float16 h8_t __attribute__((ext_vector_type(8)));
typedef float f32x4 __attribute__((ext_vector_type(4)));

// fused counted-wait + barrier, ONE asm block (r4/r5 lessons: builtin
// s_barrier is IntrNoMem; must also drain lgkmcnt before crossing).
#define WAITBAR(N) \
  asm volatile("s_waitcnt vmcnt(" #N ") lgkmcnt(0)\n\ts_barrier" ::: "memory")

// lgkm-only barrier: orders ALL LDS traffic (ds_read/ds_write are lgkm-counted)
// but leaves global prefetch loads IN FLIGHT across the barrier. This is the
// piece r2's T14 attempt was missing (__syncthreads drains vmcnt(0) -> the
// prefetch stalled collectively at every barrier).
#define BARRIER_LG \
  asm volatile("s_waitcnt lgkmcnt(0)\n\ts_barrier" ::: "memory")

// async global->LDS, 16B per lane; LDS dest must be wave-uniform base (+lane*16 implicit)
__device__ __forceinline__ void load_lds16(const void* g, void* l) {
  __builtin_amdgcn_global_load_lds(
      (const __attribute__((address_space(1))) unsigned int*)g,
      (__attribute__((address_space(3))) unsigned int*)l, 16, 0, 0);
}

// ---------------- weight transpose + fp32 -> fp16 convert ----------------
__global__ __launch_bounds__(256) void transpose_k(const float* __restrict__ in,
                                                   _Float16* __restrict__ out,
                                                   int K, int N) {
  __shared__ float tile[32][33];
  int n0 = blockIdx.x * 32, k0 = blockIdx.y * 32;
  int tx = threadIdx.x & 31, ty = threadIdx.x >> 5;
  #pragma unroll
  for (int i = 0; i < 32; i += 8)
    tile[ty + i][tx] = in[(size_t)(k0 + ty + i) * N + n0 + tx];
  __syncthreads();
  #pragma unroll
  for (int i = 0; i < 32; i += 8)
    out[(size_t)(n0 + ty + i) * K + k0 + tx] = (_Float16)tile[tx][ty + i];
}

// ---------------- LayerNorm (+fused xt ident write) ----------------
__global__ __launch_bounds__(256) void ln_kernel(const float* __restrict__ x,
                                                 const float* __restrict__ gamma,
                                                 const float* __restrict__ beta,
                                                 float* __restrict__ xn,
                                                 _Float16* __restrict__ xt) {
  int t = blockIdx.x;
  int tid = threadIdx.x;
  const float* xp = x + (size_t)t * HID;
  float v0 = xp[tid], v1 = xp[tid + 256];
  float s = v0 + v1;
  float q2 = v0 * v0 + v1 * v1;
  #pragma unroll
  for (int off = 32; off > 0; off >>= 1) {
    s += __shfl_xor(s, off);
    q2 += __shfl_xor(q2, off);
  }
  __shared__ float ls[4], lq[4];
  int w = tid >> 6;
  if ((tid & 63) == 0) { ls[w] = s; lq[w] = q2; }
  __syncthreads();
  s = ls[0] + ls[1] + ls[2] + ls[3];
  q2 = lq[0] + lq[1] + lq[2] + lq[3];
  float mu = s * (1.f / 512.f);
  float var = q2 * (1.f / 512.f) - mu * mu;
  float r = rsqrtf(var + 1e-5f);
  float o0 = (v0 - mu) * r * gamma[tid] + beta[tid];
  float o1 = (v1 - mu) * r * gamma[tid + 256] + beta[tid + 256];
  xn[(size_t)t * HID + tid] = o0;
  xn[(size_t)t * HID + tid + 256] = o1;
  xt[(size_t)t * HID + tid] = (_Float16)o0;
  if (tid < 64) xt[(size_t)t * HID + tid + 256] = (_Float16)o1;
}

// ---------------- build xt shifts only (c in [384,512)) ----------------
__global__ __launch_bounds__(256) void build_xt(const float* __restrict__ xn,
                                                _Float16* __restrict__ xt) {
  int gid = blockIdx.x * 256 + threadIdx.x;
  int c = 384 + (gid & 127);
  size_t tok = (size_t)(gid >> 7);
  int l = (int)(tok & (LSEQ - 1));
  float v;
  if (c < 448) v = (l >= 1) ? xn[(tok - 1) * HID + c] : 0.f;
  else         v = (l >= 2) ? xn[(tok - 2) * HID + c] : 0.f;
  xt[tok * HID + c] = (_Float16)v;
}

// ---------------- causal logcumsumexp scan ----------------
__global__ __launch_bounds__(256) void scan_kernel(const float* __restrict__ xn,
                                                   _Float16* __restrict__ xt) {
  int wid = (blockIdx.x * 256 + threadIdx.x) >> 6;
  int lane = threadIdx.x & 63;
  int b = wid >> 6, c = wid & 63;
  const float* src = xn + (size_t)b * LSEQ * HID + 320 + c;
  int l0 = lane * 32;
  float pm[32], ps[32];
  float m = -INFINITY, s = 0.f;
  #pragma unroll
  for (int i = 0; i < 32; ++i) {
    float a = 5.f * src[(size_t)(l0 + i) * HID];
    float mn = fmaxf(m, a);
    s = s * __expf(m - mn) + __expf(a - mn);
    m = mn;
    pm[i] = m; ps[i] = s;
  }
  float cm = m, cs = s;
  #pragma unroll
  for (int off = 1; off < 64; off <<= 1) {
    float om = __shfl_up(cm, off);
    float os = __shfl_up(cs, off);
    if (lane >= off) {
      float mn = fmaxf(om, cm);
      cs = os * __expf(om - mn) + cs * __expf(cm - mn);
      cm = mn;
    }
  }
  float em = __shfl_up(cm, 1);
  float es = __shfl_up(cs, 1);
  if (lane == 0) { em = -INFINITY; es = 0.f; }
  #pragma unroll
  for (int i = 0; i < 32; ++i) {
    float mn = fmaxf(em, pm[i]);
    float S = es * __expf(em - mn) + ps[i] * __expf(pm[i] - mn);
    float v = (mn + logf(S)) * 0.2f;
    xt[((size_t)b * LSEQ + l0 + i) * HID + 320 + c] = (_Float16)v;
  }
}

// ---------------- proj GEMM: 256x128 tile, 512 threads, XCD swizzle,
//                  LDS-transposed coalesced V stores (r10/r11, passing) ------
__global__ __launch_bounds__(512) void proj_gemm(const _Float16* __restrict__ A,
                                                 const _Float16* __restrict__ Bt,
                                                 _Float16* __restrict__ qb,
                                                 _Float16* __restrict__ kb,
                                                 _Float16* __restrict__ vT,
                                                 _Float16* __restrict__ act) {
  __shared__ __align__(16) char smem[49152];
  _Float16* AsB = (_Float16*)smem;            // 2 bufs x 8192 (32KB)
  _Float16* BsB = (_Float16*)(smem + 32768);  // 2 bufs x 4096 (16KB)
  const int tid = threadIdx.x;
  const int w = tid >> 6, lane = tid & 63;   // w in 0..7
  const int wm = w >> 1, wn = w & 1;         // 4M x 2N wave grid, 64x64 each
  const int quad = lane >> 4, li = lane & 15;
  const int bid = blockIdx.x;                // 0..447
  const int k8 = bid & 7, ci = bid >> 3;     // XCD id, chunk index 0..55
  const int bx = (k8 & 1) * 14 + (ci % 14);  // N-block 0..27
  const int by = (k8 >> 1) * 4 + (ci / 14);  // M-block 0..15
  const int M0 = by * 256, N0 = bx * 128;
  const int lr = lane >> 2;
  const int lc = (lane & 3) * 8;
  f32x4 acc[4][4] = {};
  const _Float16* Ab = A  + (size_t)(M0 + w * 32 + lr) * 512 + lc;
  const _Float16* Bb = Bt + (size_t)(N0 + w * 16 + lr) * 512 + lc;

  auto stage = [&](int buf, int k0) {
    _Float16* AsW = &AsB[buf * 8192 + (w * 32) * 32];
    _Float16* BsW = &BsB[buf * 4096 + (w * 16) * 32];
    load_lds16(Ab + k0,            AsW);
    load_lds16(Ab + 16 * 512 + k0, AsW + 16 * 32);
    load_lds16(Bb + k0,            BsW);
  };

  stage(0, 0);
  __syncthreads();
  int cur = 0;
  for (int t = 0; t < 16; ++t) {
    if (t < 15) stage(cur ^ 1, (t + 1) * 32);
    h8_t af[4], bf[4];
    #pragma unroll
    for (int i = 0; i < 4; ++i) {
      af[i] = *(const h8_t*)&AsB[cur * 8192 + (wm * 64 + i * 16 + li) * 32 + quad * 8];
      bf[i] = *(const h8_t*)&BsB[cur * 4096 + (wn * 64 + i * 16 + li) * 32 + quad * 8];
    }
    #pragma unroll
    for (int mi = 0; mi < 4; ++mi)
      #pragma unroll
      for (int ni = 0; ni < 4; ++ni)
        acc[mi][ni] = __builtin_amdgcn_mfma_f32_16x16x32_f16(af[mi], bf[ni], acc[mi][ni], 0, 0, 0);
    __syncthreads();
    cur ^= 1;
  }

  if (N0 >= 1024 && N0 < 1536) {
    // ---- V-block: LDS transpose -> coalesced vT stores ----
    _Float16* T = (_Float16*)smem;           // 128 l x 132-stride d tile (33.8KB)
    const int b = M0 >> 11;
    const int dloc = tid >> 2, l0 = (tid & 3) * 32;
    const int h = ((N0 - 1024) >> 6) + (dloc >> 6);
    const int dd = dloc & 63;
    #pragma unroll
    for (int c = 0; c < 2; ++c) {
      __syncthreads();
      if ((wm >> 1) == c) {
        const int lbase = (wm & 1) * 64;
        #pragma unroll
        for (int mi = 0; mi < 4; ++mi)
          #pragma unroll
          for (int ni = 0; ni < 4; ++ni)
            #pragma unroll
            for (int r = 0; r < 4; ++r)
              T[(lbase + mi * 16 + quad * 4 + r) * 132 + wn * 64 + ni * 16 + li] =
                  (_Float16)acc[mi][ni][r];
      }
      __syncthreads();
      _Float16* dstrow = vT + (((size_t)b * NH + h) * HD + dd) * LSEQ
                            + (M0 & (LSEQ - 1)) + c * 128;
      #pragma unroll
      for (int i = 0; i < 4; ++i) {
        h8_t v8;
        #pragma unroll
        for (int e = 0; e < 8; ++e) v8[e] = T[(l0 + i * 8 + e) * 132 + dloc];
        *(h8_t*)&dstrow[l0 + i * 8] = v8;
      }
    }
  } else {
    #pragma unroll
    for (int mi = 0; mi < 4; ++mi)
      #pragma unroll
      for (int ni = 0; ni < 4; ++ni)
        #pragma unroll
        for (int r = 0; r < 4; ++r) {
          int mrow = M0 + wm * 64 + mi * 16 + quad * 4 + r;
          int n = N0 + wn * 64 + ni * 16 + li;
          float v = acc[mi][ni][r];
          int b = mrow >> 11, l = mrow & (LSEQ - 1);
          int d = n & 63;
          if (n < 512) {
            int h = n >> 6;
            qb[(((size_t)b * NH + h) * LSEQ + l) * HD + d] = (_Float16)v;
          } else if (n < 1024) {
            int h = (n >> 6) - 8;
            kb[(((size_t)b * NH + h) * LSEQ + l) * HD + d] = (_Float16)v;
          } else {
            float g = 0.5f * v * (1.f + erff(v * 0.70710678f));
            act[(size_t)mrow * VPN + 512 + (n - 1536)] = (_Float16)g;
          }
        }
  }
}

// ---------------- flash attention, split-K=2 + ALiBi window + XCD pairing
//                  + reg-prefetch staging with lgkm-only barriers (r13) -----
// Per-tile critical path was stage-latency-bound (global load ~600-900cyc
// serial before every tile's compute; ~2-3 blocks/CU -> no TLP to hide it).
// Now tile t+1's K/V loads are issued right after tile t's staging barrier
// and fly under QK+softmax+PV. All three in-loop barriers are lgkm-only so
// the prefetch stays in flight (r2's failure was __syncthreads' vmcnt(0)).
// Ledger: (B) my ds_writes drained+barrier -> staging visible; (C) all K
// ds_reads drained before P overwrites; (A') all Vt/P reads drained before
// next iteration's ds_write. Prefetch regs are thread-private.
__global__ __launch_bounds__(256) void attn_partial(const _Float16* __restrict__ qb,
                                                    const _Float16* __restrict__ kb,
                                                    const _Float16* __restrict__ vTb,
                                                    _Float16* __restrict__ Opart,
                                                    float* __restrict__ zpart) {
  __shared__ __align__(16) _Float16 KtP[128 * 136];
  __shared__ __align__(16) _Float16 Vt[64 * 136];
  const int bid = blockIdx.x;                 // 0..511
  const int k8 = bid & 7, ci = bid >> 3;      // ci 0..63
  const int half = ci >> 5;
  const int hh = k8 & 3;
  const int bh = ((k8 & 4) << 1) + (half ? 7 - hh : hh);  // {h,7-h} pairing
  const int rr_ = ci & 31;
  const int qt = 15 - (rr_ >> 1);             // heavy-first (LPT)
  const int s = rr_ & 1;
  const int tid = threadIdx.x;
  const int w = tid >> 6, lane = tid & 63;
  const int quad = lane >> 4, li = lane & 15;
  const int h = bh & 7;
  const float LOG2E = 1.44269504f;
  const float slope2 = exp2f(-(float)(h + 1)) * LOG2E;
  const float SCALE2 = 0.125f * LOG2E;
  const _Float16* qp = qb + (size_t)bh * LSEQ * HD;
  const _Float16* kp = kb + (size_t)bh * LSEQ * HD;
  const _Float16* vp = vTb + (size_t)bh * HD * LSEQ;
  const int q0 = qt * 128;
  const int qlb = w * 32;

  // ALiBi window: first kept tile index
  const int wint = (int)(48.0f / slope2);
  const int lo = q0 - wint;
  int jt_min = lo > 0 ? lo / 128 : 0;
  int d2 = ((s - jt_min) % 2 + 2) % 2;
  const int jt0 = jt_min + d2;

  h8_t qf[2][2];
  #pragma unroll
  for (int mi = 0; mi < 2; ++mi)
    #pragma unroll
    for (int kk = 0; kk < 2; ++kk)
      qf[mi][kk] = *(const h8_t*)&qp[(size_t)(q0 + qlb + mi * 16 + li) * HD + kk * 32 + quad * 8];

  f32x4 oacc[2][4] = {};
  float mrow[2][4], lrow[2][4];
  #pragma unroll
  for (int mi = 0; mi < 2; ++mi)
    #pragma unroll
    for (int r = 0; r < 4; ++r) { mrow[mi][r] = -INFINITY; lrow[mi][r] = 0.f; }

  // staging lane geometry + prefetch registers
  const int rr = tid >> 3, ss = (tid & 7) * 8;      // K: 32 rows x 64 cols / pass
  const int dd = tid >> 4, s2 = (tid & 15) * 8;     // V: 16 rows x 128 cols / pass
  h8_t kreg[4], vreg[4];
  auto issue = [&](int j0) {
    #pragma unroll
    for (int i = 0; i < 4; ++i) {
      kreg[i] = *(const h8_t*)&kp[(size_t)(j0 + rr + i * 32) * HD + ss];
      vreg[i] = *(const h8_t*)&vp[(size_t)(dd + i * 16) * LSEQ + j0 + s2];
    }
  };

  if (jt0 <= qt) issue(jt0 * 128);

  for (int jt = jt0; jt <= qt; jt += 2) {
    const int j0 = jt * 128;
    // write prefetched regs -> LDS (compiler inserts the vmcnt wait on use)
    #pragma unroll
    for (int i = 0; i < 4; ++i) {
      *(h8_t*)&KtP[(rr + i * 32) * 72 + ss] = kreg[i];
      *(h8_t*)&Vt[(dd + i * 16) * 136 + s2] = vreg[i];
    }
    BARRIER_LG;                          // (B) staging visible to all waves
    if (jt + 2 <= qt) issue(j0 + 256);   // next tile's loads fly under compute

    f32x4 sc[2][8] = {};
    #pragma unroll
    for (int jn = 0; jn < 8; ++jn) {
      h8_t b0 = *(const h8_t*)&KtP[(jn * 16 + li) * 72 + quad * 8];
      h8_t b1 = *(const h8_t*)&KtP[(jn * 16 + li) * 72 + 32 + quad * 8];
      #pragma unroll
      for (int mi = 0; mi < 2; ++mi) {
        sc[mi][jn] = __builtin_amdgcn_mfma_f32_16x16x32_f16(qf[mi][0], b0, sc[mi][jn], 0, 0, 0);
        sc[mi][jn] = __builtin_amdgcn_mfma_f32_16x16x32_f16(qf[mi][1], b1, sc[mi][jn], 0, 0, 0);
      }
    }
    const bool diag = (jt == qt);
    float rmax[2][4];
    #pragma unroll
    for (int mi = 0; mi < 2; ++mi)
      #pragma unroll
      for (int r = 0; r < 4; ++r) rmax[mi][r] = -INFINITY;
    #pragma unroll
    for (int mi = 0; mi < 2; ++mi)
      #pragma unroll
      for (int jn = 0; jn < 8; ++jn)
        #pragma unroll
        for (int r = 0; r < 4; ++r) {
          int j = j0 + jn * 16 + li;
          float v = sc[mi][jn][r] * SCALE2 + slope2 * (float)j;
          if (diag && j > q0 + qlb + mi * 16 + quad * 4 + r) v = -1e30f;
          sc[mi][jn][r] = v;
          rmax[mi][r] = fmaxf(rmax[mi][r], v);
        }
    #pragma unroll
    for (int mi = 0; mi < 2; ++mi)
      #pragma unroll
      for (int r = 0; r < 4; ++r) {
        float v = rmax[mi][r];
        v = fmaxf(v, __shfl_xor(v, 1));
        v = fmaxf(v, __shfl_xor(v, 2));
        v = fmaxf(v, __shfl_xor(v, 4));
        v = fmaxf(v, __shfl_xor(v, 8));
        rmax[mi][r] = v;
      }
    float alpha[2][4];
    #pragma unroll
    for (int mi = 0; mi < 2; ++mi)
      #pragma unroll
      for (int r = 0; r < 4; ++r) {
        float mn = fmaxf(mrow[mi][r], rmax[mi][r]);
        alpha[mi][r] = exp2f(mrow[mi][r] - mn);
        mrow[mi][r] = mn;
      }
    float rsum[2][4] = {};
    #pragma unroll
    for (int mi = 0; mi < 2; ++mi)
      #pragma unroll
      for (int jn = 0; jn < 8; ++jn)
        #pragma unroll
        for (int r = 0; r < 4; ++r) {
          float p = exp2f(sc[mi][jn][r] - mrow[mi][r]);
          sc[mi][jn][r] = p;
          rsum[mi][r] += p;
        }
    #pragma unroll
    for (int mi = 0; mi < 2; ++mi)
      #pragma unroll
      for (int r = 0; r < 4; ++r) {
        float v = rsum[mi][r];
        v += __shfl_xor(v, 1);
        v += __shfl_xor(v, 2);
        v += __shfl_xor(v, 4);
        v += __shfl_xor(v, 8);
        lrow[mi][r] = lrow[mi][r] * alpha[mi][r] + v;
      }
    #pragma unroll
    for (int mi = 0; mi < 2; ++mi)
      #pragma unroll
      for (int ni = 0; ni < 4; ++ni)
        #pragma unroll
        for (int r = 0; r < 4; ++r) oacc[mi][ni][r] *= alpha[mi][r];

    BARRIER_LG;                          // (C) all K reads drained before P overwrite
    #pragma unroll
    for (int mi = 0; mi < 2; ++mi)
      #pragma unroll
      for (int jn = 0; jn < 8; ++jn)
        #pragma unroll
        for (int r = 0; r < 4; ++r)
          KtP[(qlb + mi * 16 + quad * 4 + r) * 136 + jn * 16 + li] = (_Float16)sc[mi][jn][r];
    #pragma unroll
    for (int kk = 0; kk < 4; ++kk) {
      h8_t pf[2];
      #pragma unroll
      for (int mi = 0; mi < 2; ++mi)
        pf[mi] = *(const h8_t*)&KtP[(qlb + mi * 16 + li) * 136 + kk * 32 + quad * 8];
      #pragma unroll
      for (int nd = 0; nd < 4; ++nd) {
        h8_t vf = *(const h8_t*)&Vt[(nd * 16 + li) * 136 + kk * 32 + quad * 8];
        #pragma unroll
        for (int mi = 0; mi < 2; ++mi)
          oacc[mi][nd] = __builtin_amdgcn_mfma_f32_16x16x32_f16(pf[mi], vf, oacc[mi][nd], 0, 0, 0);
      }
    }
    BARRIER_LG;                          // (A') all Vt/P reads drained before next ds_write
  }

  const size_t pbase = ((size_t)bh * 16 + qt) * 2 + s;
  #pragma unroll
  for (int mi = 0; mi < 2; ++mi)
    #pragma unroll
    for (int r = 0; r < 4; ++r) {
      int prow = qlb + mi * 16 + quad * 4 + r;
      float l = lrow[mi][r];
      float inv = (l > 0.f) ? 1.f / l : 0.f;
      if (li == 0)
        zpart[pbase * 128 + prow] = (l > 0.f) ? mrow[mi][r] + log2f(l) : -INFINITY;  // base-2 z
      #pragma unroll
      for (int nd = 0; nd < 4; ++nd)
        Opart[pbase * 8192 + (size_t)prow * 64 + nd * 16 + li] =
            (_Float16)(oacc[mi][nd][r] * inv);
    }
}

// ---------------- attention combine (split-2, z is base-2) ----------------
__global__ __launch_bounds__(256) void attn_combine(const _Float16* __restrict__ Opart,
                                                    const float* __restrict__ zpart,
                                                    _Float16* __restrict__ act) {
  int g = blockIdx.x * 64 + (threadIdx.x >> 2);
  int c0 = (threadIdx.x & 3) * 16;
  int bh = g >> 11, l = g & 2047;
  int qt = l >> 7, row = l & 127;
  size_t pbase = ((size_t)bh * 16 + qt) * 2;
  float z[2], wgt[2];
  float Z = -INFINITY;
  #pragma unroll
  for (int s = 0; s < 2; ++s) {
    z[s] = zpart[(pbase + s) * 128 + row];
    Z = fmaxf(Z, z[s]);
  }
  float W = 0.f;
  #pragma unroll
  for (int s = 0; s < 2; ++s) { wgt[s] = exp2f(z[s] - Z); W += wgt[s]; }
  float inv = 1.f / W;
  float acc[16] = {};
  #pragma unroll
  for (int s = 0; s < 2; ++s) {
    const h8_t* p = (const h8_t*)&Opart[(pbase + s) * 8192 + (size_t)row * 64 + c0];
    h8_t a = p[0], b = p[1];
    #pragma unroll
    for (int i = 0; i < 8; ++i) {
      acc[i] += wgt[s] * (float)a[i];
      acc[8 + i] += wgt[s] * (float)b[i];
    }
  }
  int b_ = bh >> 3, h = bh & 7;
  _Float16* dst = &act[((size_t)b_ * LSEQ + l) * VPN + h * 64 + c0];
  h8_t o0, o1;
  #pragma unroll
  for (int i = 0; i < 8; ++i) {
    o0[i] = (_Float16)(acc[i] * inv);
    o1[i] = (_Float16)(acc[8 + i] * inv);
  }
  ((h8_t*)dst)[0] = o0;
  ((h8_t*)dst)[1] = o1;
}

// ---------------- out GEMM, split-K=4, 3-buffer ring + XCD-chunked swizzle ----
__global__ __launch_bounds__(256) void out_gemm_sk(const _Float16* __restrict__ A,
                                                   const _Float16* __restrict__ Bt,
                                                   float* __restrict__ part0,
                                                   float* __restrict__ part1,
                                                   float* __restrict__ part2,
                                                   float* __restrict__ part3) {
  __shared__ __align__(16) _Float16 As[3][128 * 32];
  __shared__ __align__(16) _Float16 Bs[3][128 * 32];
  const int tid = threadIdx.x;
  const int w = tid >> 6, lane = tid & 63;
  const int wm = w >> 1, wn = w & 1;
  const int quad = lane >> 4, li = lane & 15;
  const int bid = blockIdx.x;               // 0..511
  const int k8 = bid & 7, ci = bid >> 3;    // ci 0..63
  const int sk = k8 >> 1;                   // 0..3
  const int bx = ci & 3;                    // 0..3
  const int by = (k8 & 1) * 16 + (ci >> 2); // 0..31
  const int M0 = by * 128, N0 = bx * 128;
  const int lr = lane >> 2;
  const int lc = (lane & 3) * 8;
  f32x4 acc[4][4] = {};
  const _Float16* Ab = A  + (size_t)(M0 + w * 32 + lr) * 2560 + lc;
  const _Float16* Bb = Bt + (size_t)(N0 + w * 32 + lr) * 2560 + lc;
  const int kbeg = sk * 640;

  auto stage = [&](int buf, int t) {
    const int k0 = kbeg + t * 32;
    _Float16* AsW = &As[buf][(w * 32) * 32];
    _Float16* BsW = &Bs[buf][(w * 32) * 32];
    load_lds16(Ab + k0,             AsW);
    load_lds16(Ab + 16 * 2560 + k0, AsW + 16 * 32);
    load_lds16(Bb + k0,             BsW);
    load_lds16(Bb + 16 * 2560 + k0, BsW + 16 * 32);
  };

  stage(0, 0);
  stage(1, 1);
  WAITBAR(4);
  #pragma unroll
  for (int t = 0; t < 20; ++t) {
    const int cur = t % 3;
    if (t + 2 < 20) stage((t + 2) % 3, t + 2);
    h8_t af[4], bf[4];
    #pragma unroll
    for (int i = 0; i < 4; ++i) {
      af[i] = *(const h8_t*)&As[cur][(wm * 64 + i * 16 + li) * 32 + quad * 8];
      bf[i] = *(const h8_t*)&Bs[cur][(wn * 64 + i * 16 + li) * 32 + quad * 8];
    }
    #pragma unroll
    for (int mi = 0; mi < 4; ++mi)
      #pragma unroll
      for (int ni = 0; ni < 4; ++ni)
        acc[mi][ni] = __builtin_amdgcn_mfma_f32_16x16x32_f16(af[mi], bf[ni], acc[mi][ni], 0, 0, 0);
    if (t < 19) {
      if (t + 2 < 20) WAITBAR(4);
      else            WAITBAR(0);
    }
  }
  float* dst = (sk == 0) ? part0 : (sk == 1) ? part1 : (sk == 2) ? part2 : part3;
  #pragma unroll
  for (int mi = 0; mi < 4; ++mi)
    #pragma unroll
    for (int ni = 0; ni < 4; ++ni)
      #pragma unroll
      for (int r = 0; r < 4; ++r) {
        int m = M0 + wm * 64 + mi * 16 + quad * 4 + r;
        int n = N0 + wn * 64 + ni * 16 + li;
        dst[(size_t)m * HID + n] = acc[mi][ni][r];
      }
}

// ---------------- combine split-K partials + bias ----------------
__global__ __launch_bounds__(256) void out_combine(const float* __restrict__ part0,
                                                   const float* __restrict__ part1,
                                                   const float* __restrict__ part2,
                                                   const float* __restrict__ part3,
                                                   const float* __restrict__ bias,
                                                   float* __restrict__ out) {
  int idx = (blockIdx.x * 256 + threadIdx.x) * 4;
  float4 a = *(const float4*)&part0[idx];
  float4 b = *(const float4*)&part1[idx];
  float4 c = *(const float4*)&part2[idx];
  float4 d = *(const float4*)&part3[idx];
  float4 e = *(const float4*)&bias[idx & 511];
  float4 o;
  o.x = a.x + b.x + c.x + d.x + e.x;
  o.y = a.y + b.y + c.y + d.y + e.y;
  o.z = a.z + b.z + c.z + d.z + e.z;
  o.w = a.w + b.w + c.w + d.w + e.w;
  *(float4*)&out[idx] = o;
}

extern "C" void kernel_launch(void* const* d_in, const int* in_sizes, int n_in,
                              void* d_out, int out_size, void* d_ws, size_t ws_size,
                              hipStream_t stream) {
  const float* x      = (const float*)d_in[0];
  const float* gamma  = (const float*)d_in[1];
  const float* beta   = (const float*)d_in[2];
  const float* w_in   = (const float*)d_in[3];
  const float* w_out  = (const float*)d_in[4];
  const float* b_out  = (const float*)d_in[5];
  float* out = (float*)d_out;
  char* ws = (char*)d_ws;

  float*    xn     = (float*)(ws);                    // 8,388,608 B
  _Float16* xt     = (_Float16*)(ws + 8388608);       // 4,194,304 B
  _Float16* w_inT  = (_Float16*)(ws + 12582912);      // 3,670,016 B
  _Float16* w_outT = (_Float16*)(ws + 16252928);      // 2,621,440 B
  _Float16* qb     = (_Float16*)(ws + 18874368);      // 4,194,304 B
  _Float16* kb     = (_Float16*)(ws + 23068672);      // 4,194,304 B
  _Float16* vT     = (_Float16*)(ws + 27262976);      // 4,194,304 B
  _Float16* act    = (_Float16*)(ws + 31457280);      // 20,971,520 B
  _Float16* Opart  = (_Float16*)(ws + 52428800);      // 8,388,608 B used (split-2)
  float*    zpart  = (float*)(ws + 69206016);         // 262,144 B used
  float*    opart_0 = (float*)(ws);
  float*    opart_1 = (float*)(ws + 18874368);
  float*    opart_2 = (float*)(ws + 52428800);
  float*    opart_3 = (float*)(ws + 60817408);

  transpose_k<<<dim3(QKVPN / 32, HID / 32), 256, 0, stream>>>(w_in, w_inT, HID, QKVPN);
  transpose_k<<<dim3(HID / 32, VPN / 32), 256, 0, stream>>>(w_out, w_outT, VPN, HID);
  ln_kernel<<<dim3(TOK), 256, 0, stream>>>(x, gamma, beta, xn, xt);
  build_xt<<<dim3(TOK * 128 / 256), 256, 0, stream>>>(xn, xt);
  scan_kernel<<<dim3(32), 256, 0, stream>>>(xn, xt);
  proj_gemm<<<dim3(448), 512, 0, stream>>>(xt, w_inT, qb, kb, vT, act);
  attn_partial<<<dim3(512), 256, 0, stream>>>(qb, kb, vT, Opart, zpart);
  attn_combine<<<dim3(16 * LSEQ / 64), 256, 0, stream>>>(Opart, zpart, act);
  out_gemm_sk<<<dim3(512), 256, 0, stream>>>(act, w_outT,
                                             opart_0, opart_1, opart_2, opart_3);
  out_combine<<<dim3(TOK * HID / 4 / 256), 256, 0, stream>>>(opart_0, opart_1, opart_2, opart_3,
                                                             b_out, out);
}

// Round 14
// 215.268 us; speedup vs baseline: 1.0327x; 1.0327x over previous
//
#include <hip/hip_runtime.h>
#include <cmath>

#define LSEQ 2048
#define HID 512
#define NH 8
#define HD 64
#define QKVPN 3584
#define VPN 2560
#define TOK 4096

typedef _Float16 h8_t __attribute__((ext_vector_type(8)));
typedef float f32x4 __attribute__((ext_vector_type(4)));

// fused counted-wait + barrier, ONE asm block (r4/r5 lessons: builtin
// s_barrier is IntrNoMem; must also drain lgkmcnt before crossing).
#define WAITBAR(N) \
  asm volatile("s_waitcnt vmcnt(" #N ") lgkmcnt(0)\n\ts_barrier" ::: "memory")

// async global->LDS, 16B per lane; LDS dest must be wave-uniform base (+lane*16 implicit)
__device__ __forceinline__ void load_lds16(const void* g, void* l) {
  __builtin_amdgcn_global_load_lds(
      (const __attribute__((address_space(1))) unsigned int*)g,
      (__attribute__((address_space(3))) unsigned int*)l, 16, 0, 0);
}

// ---------------- weight transpose + fp32 -> fp16 convert ----------------
__global__ __launch_bounds__(256) void transpose_k(const float* __restrict__ in,
                                                   _Float16* __restrict__ out,
                                                   int K, int N) {
  __shared__ float tile[32][33];
  int n0 = blockIdx.x * 32, k0 = blockIdx.y * 32;
  int tx = threadIdx.x & 31, ty = threadIdx.x >> 5;
  #pragma unroll
  for (int i = 0; i < 32; i += 8)
    tile[ty + i][tx] = in[(size_t)(k0 + ty + i) * N + n0 + tx];
  __syncthreads();
  #pragma unroll
  for (int i = 0; i < 32; i += 8)
    out[(size_t)(n0 + ty + i) * K + k0 + tx] = (_Float16)tile[tx][ty + i];
}

// ---------------- LayerNorm (+fused xt ident write) ----------------
__global__ __launch_bounds__(256) void ln_kernel(const float* __restrict__ x,
                                                 const float* __restrict__ gamma,
                                                 const float* __restrict__ beta,
                                                 float* __restrict__ xn,
                                                 _Float16* __restrict__ xt) {
  int t = blockIdx.x;
  int tid = threadIdx.x;
  const float* xp = x + (size_t)t * HID;
  float v0 = xp[tid], v1 = xp[tid + 256];
  float s = v0 + v1;
  float q2 = v0 * v0 + v1 * v1;
  #pragma unroll
  for (int off = 32; off > 0; off >>= 1) {
    s += __shfl_xor(s, off);
    q2 += __shfl_xor(q2, off);
  }
  __shared__ float ls[4], lq[4];
  int w = tid >> 6;
  if ((tid & 63) == 0) { ls[w] = s; lq[w] = q2; }
  __syncthreads();
  s = ls[0] + ls[1] + ls[2] + ls[3];
  q2 = lq[0] + lq[1] + lq[2] + lq[3];
  float mu = s * (1.f / 512.f);
  float var = q2 * (1.f / 512.f) - mu * mu;
  float r = rsqrtf(var + 1e-5f);
  float o0 = (v0 - mu) * r * gamma[tid] + beta[tid];
  float o1 = (v1 - mu) * r * gamma[tid + 256] + beta[tid + 256];
  xn[(size_t)t * HID + tid] = o0;
  xn[(size_t)t * HID + tid + 256] = o1;
  xt[(size_t)t * HID + tid] = (_Float16)o0;
  if (tid < 64) xt[(size_t)t * HID + tid + 256] = (_Float16)o1;
}

// ---------------- build xt shifts only (c in [384,512)) ----------------
__global__ __launch_bounds__(256) void build_xt(const float* __restrict__ xn,
                                                _Float16* __restrict__ xt) {
  int gid = blockIdx.x * 256 + threadIdx.x;
  int c = 384 + (gid & 127);
  size_t tok = (size_t)(gid >> 7);
  int l = (int)(tok & (LSEQ - 1));
  float v;
  if (c < 448) v = (l >= 1) ? xn[(tok - 1) * HID + c] : 0.f;
  else         v = (l >= 2) ? xn[(tok - 2) * HID + c] : 0.f;
  xt[tok * HID + c] = (_Float16)v;
}

// ---------------- causal logcumsumexp scan ----------------
__global__ __launch_bounds__(256) void scan_kernel(const float* __restrict__ xn,
                                                   _Float16* __restrict__ xt) {
  int wid = (blockIdx.x * 256 + threadIdx.x) >> 6;
  int lane = threadIdx.x & 63;
  int b = wid >> 6, c = wid & 63;
  const float* src = xn + (size_t)b * LSEQ * HID + 320 + c;
  int l0 = lane * 32;
  float pm[32], ps[32];
  float m = -INFINITY, s = 0.f;
  #pragma unroll
  for (int i = 0; i < 32; ++i) {
    float a = 5.f * src[(size_t)(l0 + i) * HID];
    float mn = fmaxf(m, a);
    s = s * __expf(m - mn) + __expf(a - mn);
    m = mn;
    pm[i] = m; ps[i] = s;
  }
  float cm = m, cs = s;
  #pragma unroll
  for (int off = 1; off < 64; off <<= 1) {
    float om = __shfl_up(cm, off);
    float os = __shfl_up(cs, off);
    if (lane >= off) {
      float mn = fmaxf(om, cm);
      cs = os * __expf(om - mn) + cs * __expf(cm - mn);
      cm = mn;
    }
  }
  float em = __shfl_up(cm, 1);
  float es = __shfl_up(cs, 1);
  if (lane == 0) { em = -INFINITY; es = 0.f; }
  #pragma unroll
  for (int i = 0; i < 32; ++i) {
    float mn = fmaxf(em, pm[i]);
    float S = es * __expf(em - mn) + ps[i] * __expf(pm[i] - mn);
    float v = (mn + logf(S)) * 0.2f;
    xt[((size_t)b * LSEQ + l0 + i) * HID + 320 + c] = (_Float16)v;
  }
}

// ---------------- proj GEMM: 256x128 tile, 512 threads, XCD swizzle,
//                  LDS-transposed coalesced V stores (r10/r11, passing) ------
__global__ __launch_bounds__(512) void proj_gemm(const _Float16* __restrict__ A,
                                                 const _Float16* __restrict__ Bt,
                                                 _Float16* __restrict__ qb,
                                                 _Float16* __restrict__ kb,
                                                 _Float16* __restrict__ vT,
                                                 _Float16* __restrict__ act) {
  __shared__ __align__(16) char smem[49152];
  _Float16* AsB = (_Float16*)smem;            // 2 bufs x 8192 (32KB)
  _Float16* BsB = (_Float16*)(smem + 32768);  // 2 bufs x 4096 (16KB)
  const int tid = threadIdx.x;
  const int w = tid >> 6, lane = tid & 63;   // w in 0..7
  const int wm = w >> 1, wn = w & 1;         // 4M x 2N wave grid, 64x64 each
  const int quad = lane >> 4, li = lane & 15;
  const int bid = blockIdx.x;                // 0..447
  const int k8 = bid & 7, ci = bid >> 3;     // XCD id, chunk index 0..55
  const int bx = (k8 & 1) * 14 + (ci % 14);  // N-block 0..27
  const int by = (k8 >> 1) * 4 + (ci / 14);  // M-block 0..15
  const int M0 = by * 256, N0 = bx * 128;
  const int lr = lane >> 2;
  const int lc = (lane & 3) * 8;
  f32x4 acc[4][4] = {};
  const _Float16* Ab = A  + (size_t)(M0 + w * 32 + lr) * 512 + lc;
  const _Float16* Bb = Bt + (size_t)(N0 + w * 16 + lr) * 512 + lc;

  auto stage = [&](int buf, int k0) {
    _Float16* AsW = &AsB[buf * 8192 + (w * 32) * 32];
    _Float16* BsW = &BsB[buf * 4096 + (w * 16) * 32];
    load_lds16(Ab + k0,            AsW);
    load_lds16(Ab + 16 * 512 + k0, AsW + 16 * 32);
    load_lds16(Bb + k0,            BsW);
  };

  stage(0, 0);
  __syncthreads();
  int cur = 0;
  for (int t = 0; t < 16; ++t) {
    if (t < 15) stage(cur ^ 1, (t + 1) * 32);
    h8_t af[4], bf[4];
    #pragma unroll
    for (int i = 0; i < 4; ++i) {
      af[i] = *(const h8_t*)&AsB[cur * 8192 + (wm * 64 + i * 16 + li) * 32 + quad * 8];
      bf[i] = *(const h8_t*)&BsB[cur * 4096 + (wn * 64 + i * 16 + li) * 32 + quad * 8];
    }
    #pragma unroll
    for (int mi = 0; mi < 4; ++mi)
      #pragma unroll
      for (int ni = 0; ni < 4; ++ni)
        acc[mi][ni] = __builtin_amdgcn_mfma_f32_16x16x32_f16(af[mi], bf[ni], acc[mi][ni], 0, 0, 0);
    __syncthreads();
    cur ^= 1;
  }

  if (N0 >= 1024 && N0 < 1536) {
    // ---- V-block: LDS transpose -> coalesced vT stores ----
    _Float16* T = (_Float16*)smem;           // 128 l x 132-stride d tile (33.8KB)
    const int b = M0 >> 11;
    const int dloc = tid >> 2, l0 = (tid & 3) * 32;
    const int h = ((N0 - 1024) >> 6) + (dloc >> 6);
    const int dd = dloc & 63;
    #pragma unroll
    for (int c = 0; c < 2; ++c) {
      __syncthreads();
      if ((wm >> 1) == c) {
        const int lbase = (wm & 1) * 64;
        #pragma unroll
        for (int mi = 0; mi < 4; ++mi)
          #pragma unroll
          for (int ni = 0; ni < 4; ++ni)
            #pragma unroll
            for (int r = 0; r < 4; ++r)
              T[(lbase + mi * 16 + quad * 4 + r) * 132 + wn * 64 + ni * 16 + li] =
                  (_Float16)acc[mi][ni][r];
      }
      __syncthreads();
      _Float16* dstrow = vT + (((size_t)b * NH + h) * HD + dd) * LSEQ
                            + (M0 & (LSEQ - 1)) + c * 128;
      #pragma unroll
      for (int i = 0; i < 4; ++i) {
        h8_t v8;
        #pragma unroll
        for (int e = 0; e < 8; ++e) v8[e] = T[(l0 + i * 8 + e) * 132 + dloc];
        *(h8_t*)&dstrow[l0 + i * 8] = v8;
      }
    }
  } else {
    #pragma unroll
    for (int mi = 0; mi < 4; ++mi)
      #pragma unroll
      for (int ni = 0; ni < 4; ++ni)
        #pragma unroll
        for (int r = 0; r < 4; ++r) {
          int mrow = M0 + wm * 64 + mi * 16 + quad * 4 + r;
          int n = N0 + wn * 64 + ni * 16 + li;
          float v = acc[mi][ni][r];
          int b = mrow >> 11, l = mrow & (LSEQ - 1);
          int d = n & 63;
          if (n < 512) {
            int h = n >> 6;
            qb[(((size_t)b * NH + h) * LSEQ + l) * HD + d] = (_Float16)v;
          } else if (n < 1024) {
            int h = (n >> 6) - 8;
            kb[(((size_t)b * NH + h) * LSEQ + l) * HD + d] = (_Float16)v;
          } else {
            float g = 0.5f * v * (1.f + erff(v * 0.70710678f));
            act[(size_t)mrow * VPN + 512 + (n - 1536)] = (_Float16)g;
          }
        }
  }
}

// ---------------- flash attention, split-K=2 + ALiBi window + XCD pairing
//                  + 8 waves/block (r14) -------------------------------------
// r13 post-mortem: drain-tail dominated (occupancy 6.5% avg = heavy blocks
// run nearly alone; per-tile serial chain fully exposed). r14: 512 threads /
// 8 waves, each wave owns 16 q-rows (was 32) -> per-tile critical path ~halves
// (16 vs 32 MFMA/wave, 32 vs 64 softmax scores/thread), and 16 waves/CU (2
// blocks x 8) for latency hiding. Store-through staging, plain __syncthreads
// (r12-proven). Prefetch reverted (r13: +16 VGPR, no gain).
__global__ __launch_bounds__(512) void attn_partial(const _Float16* __restrict__ qb,
                                                    const _Float16* __restrict__ kb,
                                                    const _Float16* __restrict__ vTb,
                                                    _Float16* __restrict__ Opart,
                                                    float* __restrict__ zpart) {
  __shared__ __align__(16) _Float16 KtP[128 * 136];
  __shared__ __align__(16) _Float16 Vt[64 * 136];
  const int bid = blockIdx.x;                 // 0..511
  const int k8 = bid & 7, ci = bid >> 3;      // ci 0..63
  const int half = ci >> 5;
  const int hh = k8 & 3;
  const int bh = ((k8 & 4) << 1) + (half ? 7 - hh : hh);  // {h,7-h} pairing
  const int rr_ = ci & 31;
  const int qt = 15 - (rr_ >> 1);             // heavy-first (LPT)
  const int s = rr_ & 1;
  const int tid = threadIdx.x;
  const int w = tid >> 6, lane = tid & 63;    // w in 0..7
  const int quad = lane >> 4, li = lane & 15;
  const int h = bh & 7;
  const float LOG2E = 1.44269504f;
  const float slope2 = exp2f(-(float)(h + 1)) * LOG2E;
  const float SCALE2 = 0.125f * LOG2E;
  const _Float16* qp = qb + (size_t)bh * LSEQ * HD;
  const _Float16* kp = kb + (size_t)bh * LSEQ * HD;
  const _Float16* vp = vTb + (size_t)bh * HD * LSEQ;
  const int q0 = qt * 128;
  const int qlb = w * 16;                     // 16 q-rows per wave

  // ALiBi window: first kept tile index
  const int wint = (int)(48.0f / slope2);
  const int lo = q0 - wint;
  int jt_min = lo > 0 ? lo / 128 : 0;
  int d2 = ((s - jt_min) % 2 + 2) % 2;
  const int jt0 = jt_min + d2;

  h8_t qf[2];
  #pragma unroll
  for (int kk = 0; kk < 2; ++kk)
    qf[kk] = *(const h8_t*)&qp[(size_t)(q0 + qlb + li) * HD + kk * 32 + quad * 8];

  f32x4 oacc[4] = {};
  float mrow[4], lrow[4];
  #pragma unroll
  for (int r = 0; r < 4; ++r) { mrow[r] = -INFINITY; lrow[r] = 0.f; }

  // staging lane geometry for 512 threads
  const int rr = tid >> 3, ss = (tid & 7) * 8;      // K: 64 rows x 64 cols / pass (2 passes)
  const int dd = tid >> 4, s2 = (tid & 15) * 8;     // V: 32 rows x 128 cols / pass (2 passes)

  for (int jt = jt0; jt <= qt; jt += 2) {
    const int j0 = jt * 128;
    __syncthreads();   // prev iteration's readers of KtP/Vt are done
    {
      #pragma unroll
      for (int i = 0; i < 2; ++i)
        *(h8_t*)&KtP[(rr + i * 64) * 72 + ss] = *(const h8_t*)&kp[(size_t)(j0 + rr + i * 64) * HD + ss];
      #pragma unroll
      for (int i = 0; i < 2; ++i)
        *(h8_t*)&Vt[(dd + i * 32) * 136 + s2] = *(const h8_t*)&vp[(size_t)(dd + i * 32) * LSEQ + j0 + s2];
    }
    __syncthreads();

    f32x4 sc[8] = {};
    #pragma unroll
    for (int jn = 0; jn < 8; ++jn) {
      h8_t b0 = *(const h8_t*)&KtP[(jn * 16 + li) * 72 + quad * 8];
      h8_t b1 = *(const h8_t*)&KtP[(jn * 16 + li) * 72 + 32 + quad * 8];
      sc[jn] = __builtin_amdgcn_mfma_f32_16x16x32_f16(qf[0], b0, sc[jn], 0, 0, 0);
      sc[jn] = __builtin_amdgcn_mfma_f32_16x16x32_f16(qf[1], b1, sc[jn], 0, 0, 0);
    }
    const bool diag = (jt == qt);
    float rmax[4];
    #pragma unroll
    for (int r = 0; r < 4; ++r) rmax[r] = -INFINITY;
    #pragma unroll
    for (int jn = 0; jn < 8; ++jn)
      #pragma unroll
      for (int r = 0; r < 4; ++r) {
        int j = j0 + jn * 16 + li;
        float v = sc[jn][r] * SCALE2 + slope2 * (float)j;
        if (diag && j > q0 + qlb + quad * 4 + r) v = -1e30f;
        sc[jn][r] = v;
        rmax[r] = fmaxf(rmax[r], v);
      }
    #pragma unroll
    for (int r = 0; r < 4; ++r) {
      float v = rmax[r];
      v = fmaxf(v, __shfl_xor(v, 1));
      v = fmaxf(v, __shfl_xor(v, 2));
      v = fmaxf(v, __shfl_xor(v, 4));
      v = fmaxf(v, __shfl_xor(v, 8));
      rmax[r] = v;
    }
    float alpha[4];
    #pragma unroll
    for (int r = 0; r < 4; ++r) {
      float mn = fmaxf(mrow[r], rmax[r]);
      alpha[r] = exp2f(mrow[r] - mn);
      mrow[r] = mn;
    }
    float rsum[4] = {};
    #pragma unroll
    for (int jn = 0; jn < 8; ++jn)
      #pragma unroll
      for (int r = 0; r < 4; ++r) {
        float p = exp2f(sc[jn][r] - mrow[r]);
        sc[jn][r] = p;
        rsum[r] += p;
      }
    #pragma unroll
    for (int r = 0; r < 4; ++r) {
      float v = rsum[r];
      v += __shfl_xor(v, 1);
      v += __shfl_xor(v, 2);
      v += __shfl_xor(v, 4);
      v += __shfl_xor(v, 8);
      lrow[r] = lrow[r] * alpha[r] + v;
    }
    #pragma unroll
    for (int nd = 0; nd < 4; ++nd)
      #pragma unroll
      for (int r = 0; r < 4; ++r) oacc[nd][r] *= alpha[r];

    __syncthreads();   // all waves done reading K before P overwrites it
    #pragma unroll
    for (int jn = 0; jn < 8; ++jn)
      #pragma unroll
      for (int r = 0; r < 4; ++r)
        KtP[(qlb + quad * 4 + r) * 136 + jn * 16 + li] = (_Float16)sc[jn][r];
    #pragma unroll
    for (int kk = 0; kk < 4; ++kk) {
      h8_t pf = *(const h8_t*)&KtP[(qlb + li) * 136 + kk * 32 + quad * 8];
      #pragma unroll
      for (int nd = 0; nd < 4; ++nd) {
        h8_t vf = *(const h8_t*)&Vt[(nd * 16 + li) * 136 + kk * 32 + quad * 8];
        oacc[nd] = __builtin_amdgcn_mfma_f32_16x16x32_f16(pf, vf, oacc[nd], 0, 0, 0);
      }
    }
  }

  const size_t pbase = ((size_t)bh * 16 + qt) * 2 + s;
  #pragma unroll
  for (int r = 0; r < 4; ++r) {
    int prow = qlb + quad * 4 + r;
    float l = lrow[r];
    float inv = (l > 0.f) ? 1.f / l : 0.f;
    if (li == 0)
      zpart[pbase * 128 + prow] = (l > 0.f) ? mrow[r] + log2f(l) : -INFINITY;  // base-2 z
    #pragma unroll
    for (int nd = 0; nd < 4; ++nd)
      Opart[pbase * 8192 + (size_t)prow * 64 + nd * 16 + li] =
          (_Float16)(oacc[nd][r] * inv);
  }
}

// ---------------- attention combine (split-2, z is base-2) ----------------
__global__ __launch_bounds__(256) void attn_combine(const _Float16* __restrict__ Opart,
                                                    const float* __restrict__ zpart,
                                                    _Float16* __restrict__ act) {
  int g = blockIdx.x * 64 + (threadIdx.x >> 2);
  int c0 = (threadIdx.x & 3) * 16;
  int bh = g >> 11, l = g & 2047;
  int qt = l >> 7, row = l & 127;
  size_t pbase = ((size_t)bh * 16 + qt) * 2;
  float z[2], wgt[2];
  float Z = -INFINITY;
  #pragma unroll
  for (int s = 0; s < 2; ++s) {
    z[s] = zpart[(pbase + s) * 128 + row];
    Z = fmaxf(Z, z[s]);
  }
  float W = 0.f;
  #pragma unroll
  for (int s = 0; s < 2; ++s) { wgt[s] = exp2f(z[s] - Z); W += wgt[s]; }
  float inv = 1.f / W;
  float acc[16] = {};
  #pragma unroll
  for (int s = 0; s < 2; ++s) {
    const h8_t* p = (const h8_t*)&Opart[(pbase + s) * 8192 + (size_t)row * 64 + c0];
    h8_t a = p[0], b = p[1];
    #pragma unroll
    for (int i = 0; i < 8; ++i) {
      acc[i] += wgt[s] * (float)a[i];
      acc[8 + i] += wgt[s] * (float)b[i];
    }
  }
  int b_ = bh >> 3, h = bh & 7;
  _Float16* dst = &act[((size_t)b_ * LSEQ + l) * VPN + h * 64 + c0];
  h8_t o0, o1;
  #pragma unroll
  for (int i = 0; i < 8; ++i) {
    o0[i] = (_Float16)(acc[i] * inv);
    o1[i] = (_Float16)(acc[8 + i] * inv);
  }
  ((h8_t*)dst)[0] = o0;
  ((h8_t*)dst)[1] = o1;
}

// ---------------- out GEMM, split-K=4, 3-buffer ring + XCD-chunked swizzle ----
__global__ __launch_bounds__(256) void out_gemm_sk(const _Float16* __restrict__ A,
                                                   const _Float16* __restrict__ Bt,
                                                   float* __restrict__ part0,
                                                   float* __restrict__ part1,
                                                   float* __restrict__ part2,
                                                   float* __restrict__ part3) {
  __shared__ __align__(16) _Float16 As[3][128 * 32];
  __shared__ __align__(16) _Float16 Bs[3][128 * 32];
  const int tid = threadIdx.x;
  const int w = tid >> 6, lane = tid & 63;
  const int wm = w >> 1, wn = w & 1;
  const int quad = lane >> 4, li = lane & 15;
  const int bid = blockIdx.x;               // 0..511
  const int k8 = bid & 7, ci = bid >> 3;    // ci 0..63
  const int sk = k8 >> 1;                   // 0..3
  const int bx = ci & 3;                    // 0..3
  const int by = (k8 & 1) * 16 + (ci >> 2); // 0..31
  const int M0 = by * 128, N0 = bx * 128;
  const int lr = lane >> 2;
  const int lc = (lane & 3) * 8;
  f32x4 acc[4][4] = {};
  const _Float16* Ab = A  + (size_t)(M0 + w * 32 + lr) * 2560 + lc;
  const _Float16* Bb = Bt + (size_t)(N0 + w * 32 + lr) * 2560 + lc;
  const int kbeg = sk * 640;

  auto stage = [&](int buf, int t) {
    const int k0 = kbeg + t * 32;
    _Float16* AsW = &As[buf][(w * 32) * 32];
    _Float16* BsW = &Bs[buf][(w * 32) * 32];
    load_lds16(Ab + k0,             AsW);
    load_lds16(Ab + 16 * 2560 + k0, AsW + 16 * 32);
    load_lds16(Bb + k0,             BsW);
    load_lds16(Bb + 16 * 2560 + k0, BsW + 16 * 32);
  };

  stage(0, 0);
  stage(1, 1);
  WAITBAR(4);
  #pragma unroll
  for (int t = 0; t < 20; ++t) {
    const int cur = t % 3;
    if (t + 2 < 20) stage((t + 2) % 3, t + 2);
    h8_t af[4], bf[4];
    #pragma unroll
    for (int i = 0; i < 4; ++i) {
      af[i] = *(const h8_t*)&As[cur][(wm * 64 + i * 16 + li) * 32 + quad * 8];
      bf[i] = *(const h8_t*)&Bs[cur][(wn * 64 + i * 16 + li) * 32 + quad * 8];
    }
    #pragma unroll
    for (int mi = 0; mi < 4; ++mi)
      #pragma unroll
      for (int ni = 0; ni < 4; ++ni)
        acc[mi][ni] = __builtin_amdgcn_mfma_f32_16x16x32_f16(af[mi], bf[ni], acc[mi][ni], 0, 0, 0);
    if (t < 19) {
      if (t + 2 < 20) WAITBAR(4);
      else            WAITBAR(0);
    }
  }
  float* dst = (sk == 0) ? part0 : (sk == 1) ? part1 : (sk == 2) ? part2 : part3;
  #pragma unroll
  for (int mi = 0; mi < 4; ++mi)
    #pragma unroll
    for (int ni = 0; ni < 4; ++ni)
      #pragma unroll
      for (int r = 0; r < 4; ++r) {
        int m = M0 + wm * 64 + mi * 16 + quad * 4 + r;
        int n = N0 + wn * 64 + ni * 16 + li;
        dst[(size_t)m * HID + n] = acc[mi][ni][r];
      }
}

// ---------------- combine split-K partials + bias ----------------
__global__ __launch_bounds__(256) void out_combine(const float* __restrict__ part0,
                                                   const float* __restrict__ part1,
                                                   const float* __restrict__ part2,
                                                   const float* __restrict__ part3,
                                                   const float* __restrict__ bias,
                                                   float* __restrict__ out) {
  int idx = (blockIdx.x * 256 + threadIdx.x) * 4;
  float4 a = *(const float4*)&part0[idx];
  float4 b = *(const float4*)&part1[idx];
  float4 c = *(const float4*)&part2[idx];
  float4 d = *(const float4*)&part3[idx];
  float4 e = *(const float4*)&bias[idx & 511];
  float4 o;
  o.x = a.x + b.x + c.x + d.x + e.x;
  o.y = a.y + b.y + c.y + d.y + e.y;
  o.z = a.z + b.z + c.z + d.z + e.z;
  o.w = a.w + b.w + c.w + d.w + e.w;
  *(float4*)&out[idx] = o;
}

extern "C" void kernel_launch(void* const* d_in, const int* in_sizes, int n_in,
                              void* d_out, int out_size, void* d_ws, size_t ws_size,
                              hipStream_t stream) {
  const float* x      = (const float*)d_in[0];
  const float* gamma  = (const float*)d_in[1];
  const float* beta   = (const float*)d_in[2];
  const float* w_in   = (const float*)d_in[3];
  const float* w_out  = (const float*)d_in[4];
  const float* b_out  = (const float*)d_in[5];
  float* out = (float*)d_out;
  char* ws = (char*)d_ws;

  float*    xn     = (float*)(ws);                    // 8,388,608 B
  _Float16* xt     = (_Float16*)(ws + 8388608);       // 4,194,304 B
  _Float16* w_inT  = (_Float16*)(ws + 12582912);      // 3,670,016 B
  _Float16* w_outT = (_Float16*)(ws + 16252928);      // 2,621,440 B
  _Float16* qb     = (_Float16*)(ws + 18874368);      // 4,194,304 B
  _Float16* kb     = (_Float16*)(ws + 23068672);      // 4,194,304 B
  _Float16* vT     = (_Float16*)(ws + 27262976);      // 4,194,304 B
  _Float16* act    = (_Float16*)(ws + 31457280);      // 20,971,520 B
  _Float16* Opart  = (_Float16*)(ws + 52428800);      // 8,388,608 B used (split-2)
  float*    zpart  = (float*)(ws + 69206016);         // 262,144 B used
  float*    opart_0 = (float*)(ws);
  float*    opart_1 = (float*)(ws + 18874368);
  float*    opart_2 = (float*)(ws + 52428800);
  float*    opart_3 = (float*)(ws + 60817408);

  transpose_k<<<dim3(QKVPN / 32, HID / 32), 256, 0, stream>>>(w_in, w_inT, HID, QKVPN);
  transpose_k<<<dim3(HID / 32, VPN / 32), 256, 0, stream>>>(w_out, w_outT, VPN, HID);
  ln_kernel<<<dim3(TOK), 256, 0, stream>>>(x, gamma, beta, xn, xt);
  build_xt<<<dim3(TOK * 128 / 256), 256, 0, stream>>>(xn, xt);
  scan_kernel<<<dim3(32), 256, 0, stream>>>(xn, xt);
  proj_gemm<<<dim3(448), 512, 0, stream>>>(xt, w_inT, qb, kb, vT, act);
  attn_partial<<<dim3(512), 512, 0, stream>>>(qb, kb, vT, Opart, zpart);
  attn_combine<<<dim3(16 * LSEQ / 64), 256, 0, stream>>>(Opart, zpart, act);
  out_gemm_sk<<<dim3(512), 256, 0, stream>>>(act, w_outT,
                                             opart_0, opart_1, opart_2, opart_3);
  out_combine<<<dim3(TOK * HID / 4 / 256), 256, 0, stream>>>(opart_0, opart_1, opart_2, opart_3,
                                                             b_out, out);
}

// Round 17
// 198.521 us; speedup vs baseline: 1.1198x; 1.0844x over previous
//
#include <hip/hip_runtime.h>
#include <cmath>

#define LSEQ 2048
#define HID 512
#define NH 8
#define HD 64
#define QKVPN 3584
#define VPN 2560
#define TOK 4096

typedef _Float16 h8_t __attribute__((ext_vector_type(8)));
typedef float f32x4 __attribute__((ext_vector_type(4)));

// fused counted-wait + barrier, ONE asm block (r4/r5 lessons: builtin
// s_barrier is IntrNoMem; must also drain lgkmcnt before crossing).
#define WAITBAR(N) \
  asm volatile("s_waitcnt vmcnt(" #N ") lgkmcnt(0)\n\ts_barrier" ::: "memory")

// async global->LDS, 16B per lane; LDS dest must be wave-uniform base (+lane*16 implicit)
__device__ __forceinline__ void load_lds16(const void* g, void* l) {
  __builtin_amdgcn_global_load_lds(
      (const __attribute__((address_space(1))) unsigned int*)g,
      (__attribute__((address_space(3))) unsigned int*)l, 16, 0, 0);
}

// ---------------- weight transpose + fp32 -> fp16 convert ----------------
__global__ __launch_bounds__(256) void transpose_k(const float* __restrict__ in,
                                                   _Float16* __restrict__ out,
                                                   int K, int N) {
  __shared__ float tile[32][33];
  int n0 = blockIdx.x * 32, k0 = blockIdx.y * 32;
  int tx = threadIdx.x & 31, ty = threadIdx.x >> 5;
  #pragma unroll
  for (int i = 0; i < 32; i += 8)
    tile[ty + i][tx] = in[(size_t)(k0 + ty + i) * N + n0 + tx];
  __syncthreads();
  #pragma unroll
  for (int i = 0; i < 32; i += 8)
    out[(size_t)(n0 + ty + i) * K + k0 + tx] = (_Float16)tile[tx][ty + i];
}

// ---------------- LayerNorm (+fused xt ident write) ----------------
__global__ __launch_bounds__(256) void ln_kernel(const float* __restrict__ x,
                                                 const float* __restrict__ gamma,
                                                 const float* __restrict__ beta,
                                                 float* __restrict__ xn,
                                                 _Float16* __restrict__ xt) {
  int t = blockIdx.x;
  int tid = threadIdx.x;
  const float* xp = x + (size_t)t * HID;
  float v0 = xp[tid], v1 = xp[tid + 256];
  float s = v0 + v1;
  float q2 = v0 * v0 + v1 * v1;
  #pragma unroll
  for (int off = 32; off > 0; off >>= 1) {
    s += __shfl_xor(s, off);
    q2 += __shfl_xor(q2, off);
  }
  __shared__ float ls[4], lq[4];
  int w = tid >> 6;
  if ((tid & 63) == 0) { ls[w] = s; lq[w] = q2; }
  __syncthreads();
  s = ls[0] + ls[1] + ls[2] + ls[3];
  q2 = lq[0] + lq[1] + lq[2] + lq[3];
  float mu = s * (1.f / 512.f);
  float var = q2 * (1.f / 512.f) - mu * mu;
  float r = rsqrtf(var + 1e-5f);
  float o0 = (v0 - mu) * r * gamma[tid] + beta[tid];
  float o1 = (v1 - mu) * r * gamma[tid + 256] + beta[tid + 256];
  xn[(size_t)t * HID + tid] = o0;
  xn[(size_t)t * HID + tid + 256] = o1;
  xt[(size_t)t * HID + tid] = (_Float16)o0;
  if (tid < 64) xt[(size_t)t * HID + tid + 256] = (_Float16)o1;
}

// ---------------- merged scan (blocks 0..31) + shift copy (blocks 32..2079) ----
__global__ __launch_bounds__(256) void xt_scan_shift(const float* __restrict__ xn,
                                                     _Float16* __restrict__ xt) {
  if (blockIdx.x < 32) {
    // ---- causal logcumsumexp scan (cols 320..384) ----
    int wid = (blockIdx.x * 256 + threadIdx.x) >> 6;
    int lane = threadIdx.x & 63;
    int b = wid >> 6, c = wid & 63;
    const float* src = xn + (size_t)b * LSEQ * HID + 320 + c;
    int l0 = lane * 32;
    float pm[32], ps[32];
    float m = -INFINITY, s = 0.f;
    #pragma unroll
    for (int i = 0; i < 32; ++i) {
      float a = 5.f * src[(size_t)(l0 + i) * HID];
      float mn = fmaxf(m, a);
      s = s * __expf(m - mn) + __expf(a - mn);
      m = mn;
      pm[i] = m; ps[i] = s;
    }
    float cm = m, cs = s;
    #pragma unroll
    for (int off = 1; off < 64; off <<= 1) {
      float om = __shfl_up(cm, off);
      float os = __shfl_up(cs, off);
      if (lane >= off) {
        float mn = fmaxf(om, cm);
        cs = os * __expf(om - mn) + cs * __expf(cm - mn);
        cm = mn;
      }
    }
    float em = __shfl_up(cm, 1);
    float es = __shfl_up(cs, 1);
    if (lane == 0) { em = -INFINITY; es = 0.f; }
    #pragma unroll
    for (int i = 0; i < 32; ++i) {
      float mn = fmaxf(em, pm[i]);
      float S = es * __expf(em - mn) + ps[i] * __expf(pm[i] - mn);
      float v = (mn + logf(S)) * 0.2f;
      xt[((size_t)b * LSEQ + l0 + i) * HID + 320 + c] = (_Float16)v;
    }
  } else {
    // ---- shift regions (cols 384..512) ----
    int gid = (blockIdx.x - 32) * 256 + threadIdx.x;
    int c = 384 + (gid & 127);
    size_t tok = (size_t)(gid >> 7);
    int l = (int)(tok & (LSEQ - 1));
    float v;
    if (c < 448) v = (l >= 1) ? xn[(tok - 1) * HID + c] : 0.f;
    else         v = (l >= 2) ? xn[(tok - 2) * HID + c] : 0.f;
    xt[tok * HID + c] = (_Float16)v;
  }
}

// ---------------- proj GEMM: 256x128 tile, 512 threads, XCD swizzle,
//                  LDS-transposed coalesced stores for V (r10) AND q/k (r17) --
// r16 BUG FOUND: q/k reader wrote only 2 h8 per thread (8192 of 16384 halves
// per chunk) -> cols seg*32+16..+32 stale -> absmax 0.065. Fixed: 4 h8 = 32
// contiguous halves (64B) per thread; element count now exact.
__global__ __launch_bounds__(512) void proj_gemm(const _Float16* __restrict__ A,
                                                 const _Float16* __restrict__ Bt,
                                                 _Float16* __restrict__ qb,
                                                 _Float16* __restrict__ kb,
                                                 _Float16* __restrict__ vT,
                                                 _Float16* __restrict__ act) {
  __shared__ __align__(16) char smem[49152];
  _Float16* AsB = (_Float16*)smem;            // 2 bufs x 8192 (32KB)
  _Float16* BsB = (_Float16*)(smem + 32768);  // 2 bufs x 4096 (16KB)
  const int tid = threadIdx.x;
  const int w = tid >> 6, lane = tid & 63;   // w in 0..7
  const int wm = w >> 1, wn = w & 1;         // 4M x 2N wave grid, 64x64 each
  const int quad = lane >> 4, li = lane & 15;
  const int bid = blockIdx.x;                // 0..447
  const int k8 = bid & 7, ci = bid >> 3;     // XCD id, chunk index 0..55
  const int bx = (k8 & 1) * 14 + (ci % 14);  // N-block 0..27
  const int by = (k8 >> 1) * 4 + (ci / 14);  // M-block 0..15
  const int M0 = by * 256, N0 = bx * 128;
  const int lr = lane >> 2;
  const int lc = (lane & 3) * 8;
  f32x4 acc[4][4] = {};
  const _Float16* Ab = A  + (size_t)(M0 + w * 32 + lr) * 512 + lc;
  const _Float16* Bb = Bt + (size_t)(N0 + w * 16 + lr) * 512 + lc;

  auto stage = [&](int buf, int k0) {
    _Float16* AsW = &AsB[buf * 8192 + (w * 32) * 32];
    _Float16* BsW = &BsB[buf * 4096 + (w * 16) * 32];
    load_lds16(Ab + k0,            AsW);
    load_lds16(Ab + 16 * 512 + k0, AsW + 16 * 32);
    load_lds16(Bb + k0,            BsW);
  };

  stage(0, 0);
  __syncthreads();
  int cur = 0;
  for (int t = 0; t < 16; ++t) {
    if (t < 15) stage(cur ^ 1, (t + 1) * 32);
    h8_t af[4], bf[4];
    #pragma unroll
    for (int i = 0; i < 4; ++i) {
      af[i] = *(const h8_t*)&AsB[cur * 8192 + (wm * 64 + i * 16 + li) * 32 + quad * 8];
      bf[i] = *(const h8_t*)&BsB[cur * 4096 + (wn * 64 + i * 16 + li) * 32 + quad * 8];
    }
    #pragma unroll
    for (int mi = 0; mi < 4; ++mi)
      #pragma unroll
      for (int ni = 0; ni < 4; ++ni)
        acc[mi][ni] = __builtin_amdgcn_mfma_f32_16x16x32_f16(af[mi], bf[ni], acc[mi][ni], 0, 0, 0);
    __syncthreads();
    cur ^= 1;
  }

  if (N0 < 1024) {
    // ---- q/k block: LDS roundtrip -> coalesced 64B-run stores ----
    _Float16* T = (_Float16*)smem;            // 128 x 136 x 2B = 34.8KB
    const int b = M0 >> 11;
    const bool isK = (N0 >= 512);
    const int hbase = (isK ? (N0 - 512) : N0) >> 6;   // covers heads hbase, hbase+1
    _Float16* dstb = isK ? kb : qb;
    const int lrow = tid >> 2, seg = tid & 3;          // reader: 128 rows x 4 segs
    #pragma unroll
    for (int c = 0; c < 2; ++c) {
      __syncthreads();
      if ((wm >> 1) == c) {
        const int lbase = (wm & 1) * 64;
        #pragma unroll
        for (int mi = 0; mi < 4; ++mi)
          #pragma unroll
          for (int ni = 0; ni < 4; ++ni)
            #pragma unroll
            for (int r = 0; r < 4; ++r)
              T[(lbase + mi * 16 + quad * 4 + r) * 136 + wn * 64 + ni * 16 + li] =
                  (_Float16)acc[mi][ni][r];
      }
      __syncthreads();
      const int l = (M0 & (LSEQ - 1)) + c * 128 + lrow;
      const int h = hbase + (seg >> 1);
      const h8_t* src = (const h8_t*)&T[lrow * 136 + seg * 32];
      h8_t* d8 = (h8_t*)&dstb[(((size_t)b * NH + h) * LSEQ + l) * HD + (seg & 1) * 32];
      d8[0] = src[0];
      d8[1] = src[1];
      d8[2] = src[2];
      d8[3] = src[3];
    }
  } else if (N0 < 1536) {
    // ---- V-block: LDS transpose -> coalesced vT stores (r10) ----
    _Float16* T = (_Float16*)smem;           // 128 l x 132-stride d tile (33.8KB)
    const int b = M0 >> 11;
    const int dloc = tid >> 2, l0 = (tid & 3) * 32;
    const int h = ((N0 - 1024) >> 6) + (dloc >> 6);
    const int dd = dloc & 63;
    #pragma unroll
    for (int c = 0; c < 2; ++c) {
      __syncthreads();
      if ((wm >> 1) == c) {
        const int lbase = (wm & 1) * 64;
        #pragma unroll
        for (int mi = 0; mi < 4; ++mi)
          #pragma unroll
          for (int ni = 0; ni < 4; ++ni)
            #pragma unroll
            for (int r = 0; r < 4; ++r)
              T[(lbase + mi * 16 + quad * 4 + r) * 132 + wn * 64 + ni * 16 + li] =
                  (_Float16)acc[mi][ni][r];
      }
      __syncthreads();
      _Float16* dstrow = vT + (((size_t)b * NH + h) * HD + dd) * LSEQ
                            + (M0 & (LSEQ - 1)) + c * 128;
      #pragma unroll
      for (int i = 0; i < 4; ++i) {
        h8_t v8;
        #pragma unroll
        for (int e = 0; e < 8; ++e) v8[e] = T[(l0 + i * 8 + e) * 132 + dloc];
        *(h8_t*)&dstrow[l0 + i * 8] = v8;
      }
    }
  } else {
    #pragma unroll
    for (int mi = 0; mi < 4; ++mi)
      #pragma unroll
      for (int ni = 0; ni < 4; ++ni)
        #pragma unroll
        for (int r = 0; r < 4; ++r) {
          int mrow = M0 + wm * 64 + mi * 16 + quad * 4 + r;
          int n = N0 + wn * 64 + ni * 16 + li;
          float v = acc[mi][ni][r];
          float g = 0.5f * v * (1.f + erff(v * 0.70710678f));
          act[(size_t)mrow * VPN + 512 + (n - 1536)] = (_Float16)g;
        }
  }
}

// ---------------- flash attention, split-K=2 + ALiBi window + XCD pairing
//                  + 8 waves/block (r14, passing) ----------------------------
__global__ __launch_bounds__(512) void attn_partial(const _Float16* __restrict__ qb,
                                                    const _Float16* __restrict__ kb,
                                                    const _Float16* __restrict__ vTb,
                                                    _Float16* __restrict__ Opart,
                                                    float* __restrict__ zpart) {
  __shared__ __align__(16) _Float16 KtP[128 * 136];
  __shared__ __align__(16) _Float16 Vt[64 * 136];
  const int bid = blockIdx.x;                 // 0..511
  const int k8 = bid & 7, ci = bid >> 3;      // ci 0..63
  const int half = ci >> 5;
  const int hh = k8 & 3;
  const int bh = ((k8 & 4) << 1) + (half ? 7 - hh : hh);  // {h,7-h} pairing
  const int rr_ = ci & 31;
  const int qt = 15 - (rr_ >> 1);             // heavy-first (LPT)
  const int s = rr_ & 1;
  const int tid = threadIdx.x;
  const int w = tid >> 6, lane = tid & 63;    // w in 0..7
  const int quad = lane >> 4, li = lane & 15;
  const int h = bh & 7;
  const float LOG2E = 1.44269504f;
  const float slope2 = exp2f(-(float)(h + 1)) * LOG2E;
  const float SCALE2 = 0.125f * LOG2E;
  const _Float16* qp = qb + (size_t)bh * LSEQ * HD;
  const _Float16* kp = kb + (size_t)bh * LSEQ * HD;
  const _Float16* vp = vTb + (size_t)bh * HD * LSEQ;
  const int q0 = qt * 128;
  const int qlb = w * 16;                     // 16 q-rows per wave

  const int wint = (int)(48.0f / slope2);
  const int lo = q0 - wint;
  int jt_min = lo > 0 ? lo / 128 : 0;
  int d2 = ((s - jt_min) % 2 + 2) % 2;
  const int jt0 = jt_min + d2;

  h8_t qf[2];
  #pragma unroll
  for (int kk = 0; kk < 2; ++kk)
    qf[kk] = *(const h8_t*)&qp[(size_t)(q0 + qlb + li) * HD + kk * 32 + quad * 8];

  f32x4 oacc[4] = {};
  float mrow[4], lrow[4];
  #pragma unroll
  for (int r = 0; r < 4; ++r) { mrow[r] = -INFINITY; lrow[r] = 0.f; }

  const int rr = tid >> 3, ss = (tid & 7) * 8;      // K: 64 rows x 64 cols / pass
  const int dd = tid >> 4, s2 = (tid & 15) * 8;     // V: 32 rows x 128 cols / pass

  for (int jt = jt0; jt <= qt; jt += 2) {
    const int j0 = jt * 128;
    __syncthreads();
    {
      #pragma unroll
      for (int i = 0; i < 2; ++i)
        *(h8_t*)&KtP[(rr + i * 64) * 72 + ss] = *(const h8_t*)&kp[(size_t)(j0 + rr + i * 64) * HD + ss];
      #pragma unroll
      for (int i = 0; i < 2; ++i)
        *(h8_t*)&Vt[(dd + i * 32) * 136 + s2] = *(const h8_t*)&vp[(size_t)(dd + i * 32) * LSEQ + j0 + s2];
    }
    __syncthreads();

    f32x4 sc[8] = {};
    #pragma unroll
    for (int jn = 0; jn < 8; ++jn) {
      h8_t b0 = *(const h8_t*)&KtP[(jn * 16 + li) * 72 + quad * 8];
      h8_t b1 = *(const h8_t*)&KtP[(jn * 16 + li) * 72 + 32 + quad * 8];
      sc[jn] = __builtin_amdgcn_mfma_f32_16x16x32_f16(qf[0], b0, sc[jn], 0, 0, 0);
      sc[jn] = __builtin_amdgcn_mfma_f32_16x16x32_f16(qf[1], b1, sc[jn], 0, 0, 0);
    }
    const bool diag = (jt == qt);
    float rmax[4];
    #pragma unroll
    for (int r = 0; r < 4; ++r) rmax[r] = -INFINITY;
    #pragma unroll
    for (int jn = 0; jn < 8; ++jn)
      #pragma unroll
      for (int r = 0; r < 4; ++r) {
        int j = j0 + jn * 16 + li;
        float v = sc[jn][r] * SCALE2 + slope2 * (float)j;
        if (diag && j > q0 + qlb + quad * 4 + r) v = -1e30f;
        sc[jn][r] = v;
        rmax[r] = fmaxf(rmax[r], v);
      }
    #pragma unroll
    for (int r = 0; r < 4; ++r) {
      float v = rmax[r];
      v = fmaxf(v, __shfl_xor(v, 1));
      v = fmaxf(v, __shfl_xor(v, 2));
      v = fmaxf(v, __shfl_xor(v, 4));
      v = fmaxf(v, __shfl_xor(v, 8));
      rmax[r] = v;
    }
    float alpha[4];
    #pragma unroll
    for (int r = 0; r < 4; ++r) {
      float mn = fmaxf(mrow[r], rmax[r]);
      alpha[r] = exp2f(mrow[r] - mn);
      mrow[r] = mn;
    }
    float rsum[4] = {};
    #pragma unroll
    for (int jn = 0; jn < 8; ++jn)
      #pragma unroll
      for (int r = 0; r < 4; ++r) {
        float p = exp2f(sc[jn][r] - mrow[r]);
        sc[jn][r] = p;
        rsum[r] += p;
      }
    #pragma unroll
    for (int r = 0; r < 4; ++r) {
      float v = rsum[r];
      v += __shfl_xor(v, 1);
      v += __shfl_xor(v, 2);
      v += __shfl_xor(v, 4);
      v += __shfl_xor(v, 8);
      lrow[r] = lrow[r] * alpha[r] + v;
    }
    #pragma unroll
    for (int nd = 0; nd < 4; ++nd)
      #pragma unroll
      for (int r = 0; r < 4; ++r) oacc[nd][r] *= alpha[r];

    __syncthreads();
    #pragma unroll
    for (int jn = 0; jn < 8; ++jn)
      #pragma unroll
      for (int r = 0; r < 4; ++r)
        KtP[(qlb + quad * 4 + r) * 136 + jn * 16 + li] = (_Float16)sc[jn][r];
    #pragma unroll
    for (int kk = 0; kk < 4; ++kk) {
      h8_t pf = *(const h8_t*)&KtP[(qlb + li) * 136 + kk * 32 + quad * 8];
      #pragma unroll
      for (int nd = 0; nd < 4; ++nd) {
        h8_t vf = *(const h8_t*)&Vt[(nd * 16 + li) * 136 + kk * 32 + quad * 8];
        oacc[nd] = __builtin_amdgcn_mfma_f32_16x16x32_f16(pf, vf, oacc[nd], 0, 0, 0);
      }
    }
  }

  const size_t pbase = ((size_t)bh * 16 + qt) * 2 + s;
  #pragma unroll
  for (int r = 0; r < 4; ++r) {
    int prow = qlb + quad * 4 + r;
    float l = lrow[r];
    float inv = (l > 0.f) ? 1.f / l : 0.f;
    if (li == 0)
      zpart[pbase * 128 + prow] = (l > 0.f) ? mrow[r] + log2f(l) : -INFINITY;  // base-2 z
    #pragma unroll
    for (int nd = 0; nd < 4; ++nd)
      Opart[pbase * 8192 + (size_t)prow * 64 + nd * 16 + li] =
          (_Float16)(oacc[nd][r] * inv);
  }
}

// ---------------- attention combine (split-2, z is base-2) ----------------
__global__ __launch_bounds__(256) void attn_combine(const _Float16* __restrict__ Opart,
                                                    const float* __restrict__ zpart,
                                                    _Float16* __restrict__ act) {
  int g = blockIdx.x * 64 + (threadIdx.x >> 2);
  int c0 = (threadIdx.x & 3) * 16;
  int bh = g >> 11, l = g & 2047;
  int qt = l >> 7, row = l & 127;
  size_t pbase = ((size_t)bh * 16 + qt) * 2;
  float z[2], wgt[2];
  float Z = -INFINITY;
  #pragma unroll
  for (int s = 0; s < 2; ++s) {
    z[s] = zpart[(pbase + s) * 128 + row];
    Z = fmaxf(Z, z[s]);
  }
  float W = 0.f;
  #pragma unroll
  for (int s = 0; s < 2; ++s) { wgt[s] = exp2f(z[s] - Z); W += wgt[s]; }
  float inv = 1.f / W;
  float acc[16] = {};
  #pragma unroll
  for (int s = 0; s < 2; ++s) {
    const h8_t* p = (const h8_t*)&Opart[(pbase + s) * 8192 + (size_t)row * 64 + c0];
    h8_t a = p[0], b = p[1];
    #pragma unroll
    for (int i = 0; i < 8; ++i) {
      acc[i] += wgt[s] * (float)a[i];
      acc[8 + i] += wgt[s] * (float)b[i];
    }
  }
  int b_ = bh >> 3, h = bh & 7;
  _Float16* dst = &act[((size_t)b_ * LSEQ + l) * VPN + h * 64 + c0];
  h8_t o0, o1;
  #pragma unroll
  for (int i = 0; i < 8; ++i) {
    o0[i] = (_Float16)(acc[i] * inv);
    o1[i] = (_Float16)(acc[8 + i] * inv);
  }
  ((h8_t*)dst)[0] = o0;
  ((h8_t*)dst)[1] = o1;
}

// ---------------- out GEMM, split-K=4, 3-buffer ring + XCD-chunked swizzle ----
__global__ __launch_bounds__(256) void out_gemm_sk(const _Float16* __restrict__ A,
                                                   const _Float16* __restrict__ Bt,
                                                   float* __restrict__ part0,
                                                   float* __restrict__ part1,
                                                   float* __restrict__ part2,
                                                   float* __restrict__ part3) {
  __shared__ __align__(16) _Float16 As[3][128 * 32];
  __shared__ __align__(16) _Float16 Bs[3][128 * 32];
  const int tid = threadIdx.x;
  const int w = tid >> 6, lane = tid & 63;
  const int wm = w >> 1, wn = w & 1;
  const int quad = lane >> 4, li = lane & 15;
  const int bid = blockIdx.x;               // 0..511
  const int k8 = bid & 7, ci = bid >> 3;    // ci 0..63
  const int sk = k8 >> 1;                   // 0..3
  const int bx = ci & 3;                    // 0..3
  const int by = (k8 & 1) * 16 + (ci >> 2); // 0..31
  const int M0 = by * 128, N0 = bx * 128;
  const int lr = lane >> 2;
  const int lc = (lane & 3) * 8;
  f32x4 acc[4][4] = {};
  const _Float16* Ab = A  + (size_t)(M0 + w * 32 + lr) * 2560 + lc;
  const _Float16* Bb = Bt + (size_t)(N0 + w * 32 + lr) * 2560 + lc;
  const int kbeg = sk * 640;

  auto stage = [&](int buf, int t) {
    const int k0 = kbeg + t * 32;
    _Float16* AsW = &As[buf][(w * 32) * 32];
    _Float16* BsW = &Bs[buf][(w * 32) * 32];
    load_lds16(Ab + k0,             AsW);
    load_lds16(Ab + 16 * 2560 + k0, AsW + 16 * 32);
    load_lds16(Bb + k0,             BsW);
    load_lds16(Bb + 16 * 2560 + k0, BsW + 16 * 32);
  };

  stage(0, 0);
  stage(1, 1);
  WAITBAR(4);
  #pragma unroll
  for (int t = 0; t < 20; ++t) {
    const int cur = t % 3;
    if (t + 2 < 20) stage((t + 2) % 3, t + 2);
    h8_t af[4], bf[4];
    #pragma unroll
    for (int i = 0; i < 4; ++i) {
      af[i] = *(const h8_t*)&As[cur][(wm * 64 + i * 16 + li) * 32 + quad * 8];
      bf[i] = *(const h8_t*)&Bs[cur][(wn * 64 + i * 16 + li) * 32 + quad * 8];
    }
    #pragma unroll
    for (int mi = 0; mi < 4; ++mi)
      #pragma unroll
      for (int ni = 0; ni < 4; ++ni)
        acc[mi][ni] = __builtin_amdgcn_mfma_f32_16x16x32_f16(af[mi], bf[ni], acc[mi][ni], 0, 0, 0);
    if (t < 19) {
      if (t + 2 < 20) WAITBAR(4);
      else            WAITBAR(0);
    }
  }
  float* dst = (sk == 0) ? part0 : (sk == 1) ? part1 : (sk == 2) ? part2 : part3;
  #pragma unroll
  for (int mi = 0; mi < 4; ++mi)
    #pragma unroll
    for (int ni = 0; ni < 4; ++ni)
      #pragma unroll
      for (int r = 0; r < 4; ++r) {
        int m = M0 + wm * 64 + mi * 16 + quad * 4 + r;
        int n = N0 + wn * 64 + ni * 16 + li;
        dst[(size_t)m * HID + n] = acc[mi][ni][r];
      }
}

// ---------------- combine split-K partials + bias ----------------
__global__ __launch_bounds__(256) void out_combine(const float* __restrict__ part0,
                                                   const float* __restrict__ part1,
                                                   const float* __restrict__ part2,
                                                   const float* __restrict__ part3,
                                                   const float* __restrict__ bias,
                                                   float* __restrict__ out) {
  int idx = (blockIdx.x * 256 + threadIdx.x) * 4;
  float4 a = *(const float4*)&part0[idx];
  float4 b = *(const float4*)&part1[idx];
  float4 c = *(const float4*)&part2[idx];
  float4 d = *(const float4*)&part3[idx];
  float4 e = *(const float4*)&bias[idx & 511];
  float4 o;
  o.x = a.x + b.x + c.x + d.x + e.x;
  o.y = a.y + b.y + c.y + d.y + e.y;
  o.z = a.z + b.z + c.z + d.z + e.z;
  o.w = a.w + b.w + c.w + d.w + e.w;
  *(float4*)&out[idx] = o;
}

extern "C" void kernel_launch(void* const* d_in, const int* in_sizes, int n_in,
                              void* d_out, int out_size, void* d_ws, size_t ws_size,
                              hipStream_t stream) {
  const float* x      = (const float*)d_in[0];
  const float* gamma  = (const float*)d_in[1];
  const float* beta   = (const float*)d_in[2];
  const float* w_in   = (const float*)d_in[3];
  const float* w_out  = (const float*)d_in[4];
  const float* b_out  = (const float*)d_in[5];
  float* out = (float*)d_out;
  char* ws = (char*)d_ws;

  float*    xn     = (float*)(ws);                    // 8,388,608 B
  _Float16* xt     = (_Float16*)(ws + 8388608);       // 4,194,304 B
  _Float16* w_inT  = (_Float16*)(ws + 12582912);      // 3,670,016 B
  _Float16* w_outT = (_Float16*)(ws + 16252928);      // 2,621,440 B
  _Float16* qb     = (_Float16*)(ws + 18874368);      // 4,194,304 B
  _Float16* kb     = (_Float16*)(ws + 23068672);      // 4,194,304 B
  _Float16* vT     = (_Float16*)(ws + 27262976);      // 4,194,304 B
  _Float16* act    = (_Float16*)(ws + 31457280);      // 20,971,520 B
  _Float16* Opart  = (_Float16*)(ws + 52428800);      // 8,388,608 B used (split-2)
  float*    zpart  = (float*)(ws + 69206016);         // 262,144 B used
  float*    opart_0 = (float*)(ws);
  float*    opart_1 = (float*)(ws + 18874368);
  float*    opart_2 = (float*)(ws + 52428800);
  float*    opart_3 = (float*)(ws + 60817408);

  transpose_k<<<dim3(QKVPN / 32, HID / 32), 256, 0, stream>>>(w_in, w_inT, HID, QKVPN);
  transpose_k<<<dim3(HID / 32, VPN / 32), 256, 0, stream>>>(w_out, w_outT, VPN, HID);
  ln_kernel<<<dim3(TOK), 256, 0, stream>>>(x, gamma, beta, xn, xt);
  xt_scan_shift<<<dim3(32 + TOK * 128 / 256), 256, 0, stream>>>(xn, xt);
  proj_gemm<<<dim3(448), 512, 0, stream>>>(xt, w_inT, qb, kb, vT, act);
  attn_partial<<<dim3(512), 512, 0, stream>>>(qb, kb, vT, Opart, zpart);
  attn_combine<<<dim3(16 * LSEQ / 64), 256, 0, stream>>>(Opart, zpart, act);
  out_gemm_sk<<<dim3(512), 256, 0, stream>>>(act, w_outT,
                                             opart_0, opart_1, opart_2, opart_3);
  out_combine<<<dim3(TOK * HID / 4 / 256), 256, 0, stream>>>(opart_0, opart_1, opart_2, opart_3,
                                                             b_out, out);
}

// Round 18
// 193.910 us; speedup vs baseline: 1.1464x; 1.0238x over previous
//
#include <hip/hip_runtime.h>
#include <cmath>

#define LSEQ 2048
#define HID 512
#define NH 8
#define HD 64
#define QKVPN 3584
#define VPN 2560
#define TOK 4096

typedef _Float16 h8_t __attribute__((ext_vector_type(8)));
typedef float f32x4 __attribute__((ext_vector_type(4)));

// fused counted-wait + barrier, ONE asm block (r4/r5 lessons: builtin
// s_barrier is IntrNoMem; must also drain lgkmcnt before crossing).
#define WAITBAR(N) \
  asm volatile("s_waitcnt vmcnt(" #N ") lgkmcnt(0)\n\ts_barrier" ::: "memory")

// async global->LDS, 16B per lane; LDS dest must be wave-uniform base (+lane*16 implicit)
__device__ __forceinline__ void load_lds16(const void* g, void* l) {
  __builtin_amdgcn_global_load_lds(
      (const __attribute__((address_space(1))) unsigned int*)g,
      (__attribute__((address_space(3))) unsigned int*)l, 16, 0, 0);
}

// ---------------- prep: fused ln (+xt ident) + both weight transposes --------
// r18: three independent memory-bound prologue kernels ran serially on one
// stream, each under-utilizing BW. Grid-union: blocks [0,4096) = ln,
// [4096,5888) = w_in transpose, [5888,7168) = w_out transpose.
__global__ __launch_bounds__(256) void prep_kernel(const float* __restrict__ x,
                                                   const float* __restrict__ gamma,
                                                   const float* __restrict__ beta,
                                                   const float* __restrict__ w_in,
                                                   const float* __restrict__ w_out,
                                                   float* __restrict__ xn,
                                                   _Float16* __restrict__ xt,
                                                   _Float16* __restrict__ w_inT,
                                                   _Float16* __restrict__ w_outT) {
  __shared__ __align__(16) float smem[32 * 33];   // union: ln uses 8 floats; transpose 32x33
  const int bidx = blockIdx.x;
  const int tid = threadIdx.x;
  if (bidx < TOK) {
    // ---- LayerNorm + fused xt ident write ----
    const int t = bidx;
    const float* xp = x + (size_t)t * HID;
    float v0 = xp[tid], v1 = xp[tid + 256];
    float s = v0 + v1;
    float q2 = v0 * v0 + v1 * v1;
    #pragma unroll
    for (int off = 32; off > 0; off >>= 1) {
      s += __shfl_xor(s, off);
      q2 += __shfl_xor(q2, off);
    }
    float* ls = smem;       // [4]
    float* lq = smem + 4;   // [4]
    int w = tid >> 6;
    if ((tid & 63) == 0) { ls[w] = s; lq[w] = q2; }
    __syncthreads();
    s = ls[0] + ls[1] + ls[2] + ls[3];
    q2 = lq[0] + lq[1] + lq[2] + lq[3];
    float mu = s * (1.f / 512.f);
    float var = q2 * (1.f / 512.f) - mu * mu;
    float r = rsqrtf(var + 1e-5f);
    float o0 = (v0 - mu) * r * gamma[tid] + beta[tid];
    float o1 = (v1 - mu) * r * gamma[tid + 256] + beta[tid + 256];
    xn[(size_t)t * HID + tid] = o0;
    xn[(size_t)t * HID + tid + 256] = o1;
    xt[(size_t)t * HID + tid] = (_Float16)o0;
    if (tid < 64) xt[(size_t)t * HID + tid + 256] = (_Float16)o1;
  } else {
    // ---- weight transpose + fp32 -> fp16 convert ----
    const float* in;
    _Float16* out;
    int K, N, n0, k0;
    if (bidx < TOK + 1792) {            // w_in: K=512 rows x N=3584 cols
      int b2 = bidx - TOK;
      in = w_in; out = w_inT; K = HID; N = QKVPN;
      n0 = (b2 % 112) * 32; k0 = (b2 / 112) * 32;
    } else {                            // w_out: K=2560 rows x N=512 cols
      int b3 = bidx - TOK - 1792;
      in = w_out; out = w_outT; K = VPN; N = HID;
      n0 = (b3 % 16) * 32; k0 = (b3 / 16) * 32;
    }
    float (*tile)[33] = (float (*)[33])smem;
    int tx = tid & 31, ty = tid >> 5;
    #pragma unroll
    for (int i = 0; i < 32; i += 8)
      tile[ty + i][tx] = in[(size_t)(k0 + ty + i) * N + n0 + tx];
    __syncthreads();
    #pragma unroll
    for (int i = 0; i < 32; i += 8)
      out[(size_t)(n0 + ty + i) * K + k0 + tx] = (_Float16)tile[tx][ty + i];
  }
}

// ---------------- merged scan (blocks 0..31) + shift copy (blocks 32..2079) ----
__global__ __launch_bounds__(256) void xt_scan_shift(const float* __restrict__ xn,
                                                     _Float16* __restrict__ xt) {
  if (blockIdx.x < 32) {
    // ---- causal logcumsumexp scan (cols 320..384) ----
    int wid = (blockIdx.x * 256 + threadIdx.x) >> 6;
    int lane = threadIdx.x & 63;
    int b = wid >> 6, c = wid & 63;
    const float* src = xn + (size_t)b * LSEQ * HID + 320 + c;
    int l0 = lane * 32;
    float pm[32], ps[32];
    float m = -INFINITY, s = 0.f;
    #pragma unroll
    for (int i = 0; i < 32; ++i) {
      float a = 5.f * src[(size_t)(l0 + i) * HID];
      float mn = fmaxf(m, a);
      s = s * __expf(m - mn) + __expf(a - mn);
      m = mn;
      pm[i] = m; ps[i] = s;
    }
    float cm = m, cs = s;
    #pragma unroll
    for (int off = 1; off < 64; off <<= 1) {
      float om = __shfl_up(cm, off);
      float os = __shfl_up(cs, off);
      if (lane >= off) {
        float mn = fmaxf(om, cm);
        cs = os * __expf(om - mn) + cs * __expf(cm - mn);
        cm = mn;
      }
    }
    float em = __shfl_up(cm, 1);
    float es = __shfl_up(cs, 1);
    if (lane == 0) { em = -INFINITY; es = 0.f; }
    #pragma unroll
    for (int i = 0; i < 32; ++i) {
      float mn = fmaxf(em, pm[i]);
      float S = es * __expf(em - mn) + ps[i] * __expf(pm[i] - mn);
      float v = (mn + logf(S)) * 0.2f;
      xt[((size_t)b * LSEQ + l0 + i) * HID + 320 + c] = (_Float16)v;
    }
  } else {
    // ---- shift regions (cols 384..512) ----
    int gid = (blockIdx.x - 32) * 256 + threadIdx.x;
    int c = 384 + (gid & 127);
    size_t tok = (size_t)(gid >> 7);
    int l = (int)(tok & (LSEQ - 1));
    float v;
    if (c < 448) v = (l >= 1) ? xn[(tok - 1) * HID + c] : 0.f;
    else         v = (l >= 2) ? xn[(tok - 2) * HID + c] : 0.f;
    xt[tok * HID + c] = (_Float16)v;
  }
}

// ---------------- proj GEMM: 256x128 tile, 512 threads, XCD swizzle,
//                  LDS-transposed coalesced stores for V (r10) AND q/k (r17) --
__global__ __launch_bounds__(512) void proj_gemm(const _Float16* __restrict__ A,
                                                 const _Float16* __restrict__ Bt,
                                                 _Float16* __restrict__ qb,
                                                 _Float16* __restrict__ kb,
                                                 _Float16* __restrict__ vT,
                                                 _Float16* __restrict__ act) {
  __shared__ __align__(16) char smem[49152];
  _Float16* AsB = (_Float16*)smem;            // 2 bufs x 8192 (32KB)
  _Float16* BsB = (_Float16*)(smem + 32768);  // 2 bufs x 4096 (16KB)
  const int tid = threadIdx.x;
  const int w = tid >> 6, lane = tid & 63;   // w in 0..7
  const int wm = w >> 1, wn = w & 1;         // 4M x 2N wave grid, 64x64 each
  const int quad = lane >> 4, li = lane & 15;
  const int bid = blockIdx.x;                // 0..447
  const int k8 = bid & 7, ci = bid >> 3;     // XCD id, chunk index 0..55
  const int bx = (k8 & 1) * 14 + (ci % 14);  // N-block 0..27
  const int by = (k8 >> 1) * 4 + (ci / 14);  // M-block 0..15
  const int M0 = by * 256, N0 = bx * 128;
  const int lr = lane >> 2;
  const int lc = (lane & 3) * 8;
  f32x4 acc[4][4] = {};
  const _Float16* Ab = A  + (size_t)(M0 + w * 32 + lr) * 512 + lc;
  const _Float16* Bb = Bt + (size_t)(N0 + w * 16 + lr) * 512 + lc;

  auto stage = [&](int buf, int k0) {
    _Float16* AsW = &AsB[buf * 8192 + (w * 32) * 32];
    _Float16* BsW = &BsB[buf * 4096 + (w * 16) * 32];
    load_lds16(Ab + k0,            AsW);
    load_lds16(Ab + 16 * 512 + k0, AsW + 16 * 32);
    load_lds16(Bb + k0,            BsW);
  };

  stage(0, 0);
  __syncthreads();
  int cur = 0;
  for (int t = 0; t < 16; ++t) {
    if (t < 15) stage(cur ^ 1, (t + 1) * 32);
    h8_t af[4], bf[4];
    #pragma unroll
    for (int i = 0; i < 4; ++i) {
      af[i] = *(const h8_t*)&AsB[cur * 8192 + (wm * 64 + i * 16 + li) * 32 + quad * 8];
      bf[i] = *(const h8_t*)&BsB[cur * 4096 + (wn * 64 + i * 16 + li) * 32 + quad * 8];
    }
    #pragma unroll
    for (int mi = 0; mi < 4; ++mi)
      #pragma unroll
      for (int ni = 0; ni < 4; ++ni)
        acc[mi][ni] = __builtin_amdgcn_mfma_f32_16x16x32_f16(af[mi], bf[ni], acc[mi][ni], 0, 0, 0);
    __syncthreads();
    cur ^= 1;
  }

  if (N0 < 1024) {
    // ---- q/k block: LDS roundtrip -> coalesced 64B-run stores (r17) ----
    _Float16* T = (_Float16*)smem;            // 128 x 136 x 2B = 34.8KB
    const int b = M0 >> 11;
    const bool isK = (N0 >= 512);
    const int hbase = (isK ? (N0 - 512) : N0) >> 6;
    _Float16* dstb = isK ? kb : qb;
    const int lrow = tid >> 2, seg = tid & 3;
    #pragma unroll
    for (int c = 0; c < 2; ++c) {
      __syncthreads();
      if ((wm >> 1) == c) {
        const int lbase = (wm & 1) * 64;
        #pragma unroll
        for (int mi = 0; mi < 4; ++mi)
          #pragma unroll
          for (int ni = 0; ni < 4; ++ni)
            #pragma unroll
            for (int r = 0; r < 4; ++r)
              T[(lbase + mi * 16 + quad * 4 + r) * 136 + wn * 64 + ni * 16 + li] =
                  (_Float16)acc[mi][ni][r];
      }
      __syncthreads();
      const int l = (M0 & (LSEQ - 1)) + c * 128 + lrow;
      const int h = hbase + (seg >> 1);
      const h8_t* src = (const h8_t*)&T[lrow * 136 + seg * 32];
      h8_t* d8 = (h8_t*)&dstb[(((size_t)b * NH + h) * LSEQ + l) * HD + (seg & 1) * 32];
      d8[0] = src[0];
      d8[1] = src[1];
      d8[2] = src[2];
      d8[3] = src[3];
    }
  } else if (N0 < 1536) {
    // ---- V-block: LDS transpose -> coalesced vT stores (r10) ----
    _Float16* T = (_Float16*)smem;           // 128 l x 132-stride d tile (33.8KB)
    const int b = M0 >> 11;
    const int dloc = tid >> 2, l0 = (tid & 3) * 32;
    const int h = ((N0 - 1024) >> 6) + (dloc >> 6);
    const int dd = dloc & 63;
    #pragma unroll
    for (int c = 0; c < 2; ++c) {
      __syncthreads();
      if ((wm >> 1) == c) {
        const int lbase = (wm & 1) * 64;
        #pragma unroll
        for (int mi = 0; mi < 4; ++mi)
          #pragma unroll
          for (int ni = 0; ni < 4; ++ni)
            #pragma unroll
            for (int r = 0; r < 4; ++r)
              T[(lbase + mi * 16 + quad * 4 + r) * 132 + wn * 64 + ni * 16 + li] =
                  (_Float16)acc[mi][ni][r];
      }
      __syncthreads();
      _Float16* dstrow = vT + (((size_t)b * NH + h) * HD + dd) * LSEQ
                            + (M0 & (LSEQ - 1)) + c * 128;
      #pragma unroll
      for (int i = 0; i < 4; ++i) {
        h8_t v8;
        #pragma unroll
        for (int e = 0; e < 8; ++e) v8[e] = T[(l0 + i * 8 + e) * 132 + dloc];
        *(h8_t*)&dstrow[l0 + i * 8] = v8;
      }
    }
  } else {
    #pragma unroll
    for (int mi = 0; mi < 4; ++mi)
      #pragma unroll
      for (int ni = 0; ni < 4; ++ni)
        #pragma unroll
        for (int r = 0; r < 4; ++r) {
          int mrow = M0 + wm * 64 + mi * 16 + quad * 4 + r;
          int n = N0 + wn * 64 + ni * 16 + li;
          float v = acc[mi][ni][r];
          float g = 0.5f * v * (1.f + erff(v * 0.70710678f));
          act[(size_t)mrow * VPN + 512 + (n - 1536)] = (_Float16)g;
        }
  }
}

// ---------------- flash attention, split-K=2 + ALiBi window + XCD pairing
//                  + 8 waves/block (r14, passing) ----------------------------
__global__ __launch_bounds__(512) void attn_partial(const _Float16* __restrict__ qb,
                                                    const _Float16* __restrict__ kb,
                                                    const _Float16* __restrict__ vTb,
                                                    _Float16* __restrict__ Opart,
                                                    float* __restrict__ zpart) {
  __shared__ __align__(16) _Float16 KtP[128 * 136];
  __shared__ __align__(16) _Float16 Vt[64 * 136];
  const int bid = blockIdx.x;                 // 0..511
  const int k8 = bid & 7, ci = bid >> 3;      // ci 0..63
  const int half = ci >> 5;
  const int hh = k8 & 3;
  const int bh = ((k8 & 4) << 1) + (half ? 7 - hh : hh);  // {h,7-h} pairing
  const int rr_ = ci & 31;
  const int qt = 15 - (rr_ >> 1);             // heavy-first (LPT)
  const int s = rr_ & 1;
  const int tid = threadIdx.x;
  const int w = tid >> 6, lane = tid & 63;    // w in 0..7
  const int quad = lane >> 4, li = lane & 15;
  const int h = bh & 7;
  const float LOG2E = 1.44269504f;
  const float slope2 = exp2f(-(float)(h + 1)) * LOG2E;
  const float SCALE2 = 0.125f * LOG2E;
  const _Float16* qp = qb + (size_t)bh * LSEQ * HD;
  const _Float16* kp = kb + (size_t)bh * LSEQ * HD;
  const _Float16* vp = vTb + (size_t)bh * HD * LSEQ;
  const int q0 = qt * 128;
  const int qlb = w * 16;                     // 16 q-rows per wave

  const int wint = (int)(48.0f / slope2);
  const int lo = q0 - wint;
  int jt_min = lo > 0 ? lo / 128 : 0;
  int d2 = ((s - jt_min) % 2 + 2) % 2;
  const int jt0 = jt_min + d2;

  h8_t qf[2];
  #pragma unroll
  for (int kk = 0; kk < 2; ++kk)
    qf[kk] = *(const h8_t*)&qp[(size_t)(q0 + qlb + li) * HD + kk * 32 + quad * 8];

  f32x4 oacc[4] = {};
  float mrow[4], lrow[4];
  #pragma unroll
  for (int r = 0; r < 4; ++r) { mrow[r] = -INFINITY; lrow[r] = 0.f; }

  const int rr = tid >> 3, ss = (tid & 7) * 8;      // K: 64 rows x 64 cols / pass
  const int dd = tid >> 4, s2 = (tid & 15) * 8;     // V: 32 rows x 128 cols / pass

  for (int jt = jt0; jt <= qt; jt += 2) {
    const int j0 = jt * 128;
    __syncthreads();
    {
      #pragma unroll
      for (int i = 0; i < 2; ++i)
        *(h8_t*)&KtP[(rr + i * 64) * 72 + ss] = *(const h8_t*)&kp[(size_t)(j0 + rr + i * 64) * HD + ss];
      #pragma unroll
      for (int i = 0; i < 2; ++i)
        *(h8_t*)&Vt[(dd + i * 32) * 136 + s2] = *(const h8_t*)&vp[(size_t)(dd + i * 32) * LSEQ + j0 + s2];
    }
    __syncthreads();

    f32x4 sc[8] = {};
    #pragma unroll
    for (int jn = 0; jn < 8; ++jn) {
      h8_t b0 = *(const h8_t*)&KtP[(jn * 16 + li) * 72 + quad * 8];
      h8_t b1 = *(const h8_t*)&KtP[(jn * 16 + li) * 72 + 32 + quad * 8];
      sc[jn] = __builtin_amdgcn_mfma_f32_16x16x32_f16(qf[0], b0, sc[jn], 0, 0, 0);
      sc[jn] = __builtin_amdgcn_mfma_f32_16x16x32_f16(qf[1], b1, sc[jn], 0, 0, 0);
    }
    const bool diag = (jt == qt);
    float rmax[4];
    #pragma unroll
    for (int r = 0; r < 4; ++r) rmax[r] = -INFINITY;
    #pragma unroll
    for (int jn = 0; jn < 8; ++jn)
      #pragma unroll
      for (int r = 0; r < 4; ++r) {
        int j = j0 + jn * 16 + li;
        float v = sc[jn][r] * SCALE2 + slope2 * (float)j;
        if (diag && j > q0 + qlb + quad * 4 + r) v = -1e30f;
        sc[jn][r] = v;
        rmax[r] = fmaxf(rmax[r], v);
      }
    #pragma unroll
    for (int r = 0; r < 4; ++r) {
      float v = rmax[r];
      v = fmaxf(v, __shfl_xor(v, 1));
      v = fmaxf(v, __shfl_xor(v, 2));
      v = fmaxf(v, __shfl_xor(v, 4));
      v = fmaxf(v, __shfl_xor(v, 8));
      rmax[r] = v;
    }
    float alpha[4];
    #pragma unroll
    for (int r = 0; r < 4; ++r) {
      float mn = fmaxf(mrow[r], rmax[r]);
      alpha[r] = exp2f(mrow[r] - mn);
      mrow[r] = mn;
    }
    float rsum[4] = {};
    #pragma unroll
    for (int jn = 0; jn < 8; ++jn)
      #pragma unroll
      for (int r = 0; r < 4; ++r) {
        float p = exp2f(sc[jn][r] - mrow[r]);
        sc[jn][r] = p;
        rsum[r] += p;
      }
    #pragma unroll
    for (int r = 0; r < 4; ++r) {
      float v = rsum[r];
      v += __shfl_xor(v, 1);
      v += __shfl_xor(v, 2);
      v += __shfl_xor(v, 4);
      v += __shfl_xor(v, 8);
      lrow[r] = lrow[r] * alpha[r] + v;
    }
    #pragma unroll
    for (int nd = 0; nd < 4; ++nd)
      #pragma unroll
      for (int r = 0; r < 4; ++r) oacc[nd][r] *= alpha[r];

    __syncthreads();
    #pragma unroll
    for (int jn = 0; jn < 8; ++jn)
      #pragma unroll
      for (int r = 0; r < 4; ++r)
        KtP[(qlb + quad * 4 + r) * 136 + jn * 16 + li] = (_Float16)sc[jn][r];
    #pragma unroll
    for (int kk = 0; kk < 4; ++kk) {
      h8_t pf = *(const h8_t*)&KtP[(qlb + li) * 136 + kk * 32 + quad * 8];
      #pragma unroll
      for (int nd = 0; nd < 4; ++nd) {
        h8_t vf = *(const h8_t*)&Vt[(nd * 16 + li) * 136 + kk * 32 + quad * 8];
        oacc[nd] = __builtin_amdgcn_mfma_f32_16x16x32_f16(pf, vf, oacc[nd], 0, 0, 0);
      }
    }
  }

  const size_t pbase = ((size_t)bh * 16 + qt) * 2 + s;
  #pragma unroll
  for (int r = 0; r < 4; ++r) {
    int prow = qlb + quad * 4 + r;
    float l = lrow[r];
    float inv = (l > 0.f) ? 1.f / l : 0.f;
    if (li == 0)
      zpart[pbase * 128 + prow] = (l > 0.f) ? mrow[r] + log2f(l) : -INFINITY;  // base-2 z
    #pragma unroll
    for (int nd = 0; nd < 4; ++nd)
      Opart[pbase * 8192 + (size_t)prow * 64 + nd * 16 + li] =
          (_Float16)(oacc[nd][r] * inv);
  }
}

// ---------------- attention combine (split-2, z is base-2) ----------------
__global__ __launch_bounds__(256) void attn_combine(const _Float16* __restrict__ Opart,
                                                    const float* __restrict__ zpart,
                                                    _Float16* __restrict__ act) {
  int g = blockIdx.x * 64 + (threadIdx.x >> 2);
  int c0 = (threadIdx.x & 3) * 16;
  int bh = g >> 11, l = g & 2047;
  int qt = l >> 7, row = l & 127;
  size_t pbase = ((size_t)bh * 16 + qt) * 2;
  float z[2], wgt[2];
  float Z = -INFINITY;
  #pragma unroll
  for (int s = 0; s < 2; ++s) {
    z[s] = zpart[(pbase + s) * 128 + row];
    Z = fmaxf(Z, z[s]);
  }
  float W = 0.f;
  #pragma unroll
  for (int s = 0; s < 2; ++s) { wgt[s] = exp2f(z[s] - Z); W += wgt[s]; }
  float inv = 1.f / W;
  float acc[16] = {};
  #pragma unroll
  for (int s = 0; s < 2; ++s) {
    const h8_t* p = (const h8_t*)&Opart[(pbase + s) * 8192 + (size_t)row * 64 + c0];
    h8_t a = p[0], b = p[1];
    #pragma unroll
    for (int i = 0; i < 8; ++i) {
      acc[i] += wgt[s] * (float)a[i];
      acc[8 + i] += wgt[s] * (float)b[i];
    }
  }
  int b_ = bh >> 3, h = bh & 7;
  _Float16* dst = &act[((size_t)b_ * LSEQ + l) * VPN + h * 64 + c0];
  h8_t o0, o1;
  #pragma unroll
  for (int i = 0; i < 8; ++i) {
    o0[i] = (_Float16)(acc[i] * inv);
    o1[i] = (_Float16)(acc[8 + i] * inv);
  }
  ((h8_t*)dst)[0] = o0;
  ((h8_t*)dst)[1] = o1;
}

// ---------------- out GEMM, split-K=4, 3-buffer ring + XCD-chunked swizzle ----
__global__ __launch_bounds__(256) void out_gemm_sk(const _Float16* __restrict__ A,
                                                   const _Float16* __restrict__ Bt,
                                                   float* __restrict__ part0,
                                                   float* __restrict__ part1,
                                                   float* __restrict__ part2,
                                                   float* __restrict__ part3) {
  __shared__ __align__(16) _Float16 As[3][128 * 32];
  __shared__ __align__(16) _Float16 Bs[3][128 * 32];
  const int tid = threadIdx.x;
  const int w = tid >> 6, lane = tid & 63;
  const int wm = w >> 1, wn = w & 1;
  const int quad = lane >> 4, li = lane & 15;
  const int bid = blockIdx.x;               // 0..511
  const int k8 = bid & 7, ci = bid >> 3;    // ci 0..63
  const int sk = k8 >> 1;                   // 0..3
  const int bx = ci & 3;                    // 0..3
  const int by = (k8 & 1) * 16 + (ci >> 2); // 0..31
  const int M0 = by * 128, N0 = bx * 128;
  const int lr = lane >> 2;
  const int lc = (lane & 3) * 8;
  f32x4 acc[4][4] = {};
  const _Float16* Ab = A  + (size_t)(M0 + w * 32 + lr) * 2560 + lc;
  const _Float16* Bb = Bt + (size_t)(N0 + w * 32 + lr) * 2560 + lc;
  const int kbeg = sk * 640;

  auto stage = [&](int buf, int t) {
    const int k0 = kbeg + t * 32;
    _Float16* AsW = &As[buf][(w * 32) * 32];
    _Float16* BsW = &Bs[buf][(w * 32) * 32];
    load_lds16(Ab + k0,             AsW);
    load_lds16(Ab + 16 * 2560 + k0, AsW + 16 * 32);
    load_lds16(Bb + k0,             BsW);
    load_lds16(Bb + 16 * 2560 + k0, BsW + 16 * 32);
  };

  stage(0, 0);
  stage(1, 1);
  WAITBAR(4);
  #pragma unroll
  for (int t = 0; t < 20; ++t) {
    const int cur = t % 3;
    if (t + 2 < 20) stage((t + 2) % 3, t + 2);
    h8_t af[4], bf[4];
    #pragma unroll
    for (int i = 0; i < 4; ++i) {
      af[i] = *(const h8_t*)&As[cur][(wm * 64 + i * 16 + li) * 32 + quad * 8];
      bf[i] = *(const h8_t*)&Bs[cur][(wn * 64 + i * 16 + li) * 32 + quad * 8];
    }
    #pragma unroll
    for (int mi = 0; mi < 4; ++mi)
      #pragma unroll
      for (int ni = 0; ni < 4; ++ni)
        acc[mi][ni] = __builtin_amdgcn_mfma_f32_16x16x32_f16(af[mi], bf[ni], acc[mi][ni], 0, 0, 0);
    if (t < 19) {
      if (t + 2 < 20) WAITBAR(4);
      else            WAITBAR(0);
    }
  }
  float* dst = (sk == 0) ? part0 : (sk == 1) ? part1 : (sk == 2) ? part2 : part3;
  #pragma unroll
  for (int mi = 0; mi < 4; ++mi)
    #pragma unroll
    for (int ni = 0; ni < 4; ++ni)
      #pragma unroll
      for (int r = 0; r < 4; ++r) {
        int m = M0 + wm * 64 + mi * 16 + quad * 4 + r;
        int n = N0 + wn * 64 + ni * 16 + li;
        dst[(size_t)m * HID + n] = acc[mi][ni][r];
      }
}

// ---------------- combine split-K partials + bias ----------------
__global__ __launch_bounds__(256) void out_combine(const float* __restrict__ part0,
                                                   const float* __restrict__ part1,
                                                   const float* __restrict__ part2,
                                                   const float* __restrict__ part3,
                                                   const float* __restrict__ bias,
                                                   float* __restrict__ out) {
  int idx = (blockIdx.x * 256 + threadIdx.x) * 4;
  float4 a = *(const float4*)&part0[idx];
  float4 b = *(const float4*)&part1[idx];
  float4 c = *(const float4*)&part2[idx];
  float4 d = *(const float4*)&part3[idx];
  float4 e = *(const float4*)&bias[idx & 511];
  float4 o;
  o.x = a.x + b.x + c.x + d.x + e.x;
  o.y = a.y + b.y + c.y + d.y + e.y;
  o.z = a.z + b.z + c.z + d.z + e.z;
  o.w = a.w + b.w + c.w + d.w + e.w;
  *(float4*)&out[idx] = o;
}

extern "C" void kernel_launch(void* const* d_in, const int* in_sizes, int n_in,
                              void* d_out, int out_size, void* d_ws, size_t ws_size,
                              hipStream_t stream) {
  const float* x      = (const float*)d_in[0];
  const float* gamma  = (const float*)d_in[1];
  const float* beta   = (const float*)d_in[2];
  const float* w_in   = (const float*)d_in[3];
  const float* w_out  = (const float*)d_in[4];
  const float* b_out  = (const float*)d_in[5];
  float* out = (float*)d_out;
  char* ws = (char*)d_ws;

  float*    xn     = (float*)(ws);                    // 8,388,608 B
  _Float16* xt     = (_Float16*)(ws + 8388608);       // 4,194,304 B
  _Float16* w_inT  = (_Float16*)(ws + 12582912);      // 3,670,016 B
  _Float16* w_outT = (_Float16*)(ws + 16252928);      // 2,621,440 B
  _Float16* qb     = (_Float16*)(ws + 18874368);      // 4,194,304 B
  _Float16* kb     = (_Float16*)(ws + 23068672);      // 4,194,304 B
  _Float16* vT     = (_Float16*)(ws + 27262976);      // 4,194,304 B
  _Float16* act    = (_Float16*)(ws + 31457280);      // 20,971,520 B
  _Float16* Opart  = (_Float16*)(ws + 52428800);      // 8,388,608 B used (split-2)
  float*    zpart  = (float*)(ws + 69206016);         // 262,144 B used
  float*    opart_0 = (float*)(ws);
  float*    opart_1 = (float*)(ws + 18874368);
  float*    opart_2 = (float*)(ws + 52428800);
  float*    opart_3 = (float*)(ws + 60817408);

  prep_kernel<<<dim3(TOK + 1792 + 1280), 256, 0, stream>>>(x, gamma, beta, w_in, w_out,
                                                           xn, xt, w_inT, w_outT);
  xt_scan_shift<<<dim3(32 + TOK * 128 / 256), 256, 0, stream>>>(xn, xt);
  proj_gemm<<<dim3(448), 512, 0, stream>>>(xt, w_inT, qb, kb, vT, act);
  attn_partial<<<dim3(512), 512, 0, stream>>>(qb, kb, vT, Opart, zpart);
  attn_combine<<<dim3(16 * LSEQ / 64), 256, 0, stream>>>(Opart, zpart, act);
  out_gemm_sk<<<dim3(512), 256, 0, stream>>>(act, w_outT,
                                             opart_0, opart_1, opart_2, opart_3);
  out_combine<<<dim3(TOK * HID / 4 / 256), 256, 0, stream>>>(opart_0, opart_1, opart_2, opart_3,
                                                             b_out, out);
}

// Round 19
// 192.479 us; speedup vs baseline: 1.1550x; 1.0074x over previous
//
#include <hip/hip_runtime.h>
#include <cmath>

#define LSEQ 2048
#define HID 512
#define NH 8
#define HD 64
#define QKVPN 3584
#define VPN 2560
#define TOK 4096

typedef _Float16 h8_t __attribute__((ext_vector_type(8)));
typedef float f32x4 __attribute__((ext_vector_type(4)));

// fused counted-wait + barrier, ONE asm block (r4/r5 lessons: builtin
// s_barrier is IntrNoMem; must also drain lgkmcnt before crossing).
#define WAITBAR(N) \
  asm volatile("s_waitcnt vmcnt(" #N ") lgkmcnt(0)\n\ts_barrier" ::: "memory")

// lgkm-only barrier: orders ALL LDS traffic but leaves global prefetch loads
// in flight across the barrier (r13-proven correct; r13's perf loss was VGPR
// occupancy, which does not apply at the 8-wave VGPR=64 base).
#define BARRIER_LG \
  asm volatile("s_waitcnt lgkmcnt(0)\n\ts_barrier" ::: "memory")

// async global->LDS, 16B per lane; LDS dest must be wave-uniform base (+lane*16 implicit)
__device__ __forceinline__ void load_lds16(const void* g, void* l) {
  __builtin_amdgcn_global_load_lds(
      (const __attribute__((address_space(1))) unsigned int*)g,
      (__attribute__((address_space(3))) unsigned int*)l, 16, 0, 0);
}

// ---------------- prep: fused ln (+xt ident) + both weight transposes (r18) --
__global__ __launch_bounds__(256) void prep_kernel(const float* __restrict__ x,
                                                   const float* __restrict__ gamma,
                                                   const float* __restrict__ beta,
                                                   const float* __restrict__ w_in,
                                                   const float* __restrict__ w_out,
                                                   float* __restrict__ xn,
                                                   _Float16* __restrict__ xt,
                                                   _Float16* __restrict__ w_inT,
                                                   _Float16* __restrict__ w_outT) {
  __shared__ __align__(16) float smem[32 * 33];
  const int bidx = blockIdx.x;
  const int tid = threadIdx.x;
  if (bidx < TOK) {
    const int t = bidx;
    const float* xp = x + (size_t)t * HID;
    float v0 = xp[tid], v1 = xp[tid + 256];
    float s = v0 + v1;
    float q2 = v0 * v0 + v1 * v1;
    #pragma unroll
    for (int off = 32; off > 0; off >>= 1) {
      s += __shfl_xor(s, off);
      q2 += __shfl_xor(q2, off);
    }
    float* ls = smem;
    float* lq = smem + 4;
    int w = tid >> 6;
    if ((tid & 63) == 0) { ls[w] = s; lq[w] = q2; }
    __syncthreads();
    s = ls[0] + ls[1] + ls[2] + ls[3];
    q2 = lq[0] + lq[1] + lq[2] + lq[3];
    float mu = s * (1.f / 512.f);
    float var = q2 * (1.f / 512.f) - mu * mu;
    float r = rsqrtf(var + 1e-5f);
    float o0 = (v0 - mu) * r * gamma[tid] + beta[tid];
    float o1 = (v1 - mu) * r * gamma[tid + 256] + beta[tid + 256];
    xn[(size_t)t * HID + tid] = o0;
    xn[(size_t)t * HID + tid + 256] = o1;
    xt[(size_t)t * HID + tid] = (_Float16)o0;
    if (tid < 64) xt[(size_t)t * HID + tid + 256] = (_Float16)o1;
  } else {
    const float* in;
    _Float16* out;
    int K, N, n0, k0;
    if (bidx < TOK + 1792) {
      int b2 = bidx - TOK;
      in = w_in; out = w_inT; K = HID; N = QKVPN;
      n0 = (b2 % 112) * 32; k0 = (b2 / 112) * 32;
    } else {
      int b3 = bidx - TOK - 1792;
      in = w_out; out = w_outT; K = VPN; N = HID;
      n0 = (b3 % 16) * 32; k0 = (b3 / 16) * 32;
    }
    float (*tile)[33] = (float (*)[33])smem;
    int tx = tid & 31, ty = tid >> 5;
    #pragma unroll
    for (int i = 0; i < 32; i += 8)
      tile[ty + i][tx] = in[(size_t)(k0 + ty + i) * N + n0 + tx];
    __syncthreads();
    #pragma unroll
    for (int i = 0; i < 32; i += 8)
      out[(size_t)(n0 + ty + i) * K + k0 + tx] = (_Float16)tile[tx][ty + i];
  }
}

// ---------------- merged scan (blocks 0..31) + shift copy (blocks 32..2079) ----
__global__ __launch_bounds__(256) void xt_scan_shift(const float* __restrict__ xn,
                                                     _Float16* __restrict__ xt) {
  if (blockIdx.x < 32) {
    int wid = (blockIdx.x * 256 + threadIdx.x) >> 6;
    int lane = threadIdx.x & 63;
    int b = wid >> 6, c = wid & 63;
    const float* src = xn + (size_t)b * LSEQ * HID + 320 + c;
    int l0 = lane * 32;
    float pm[32], ps[32];
    float m = -INFINITY, s = 0.f;
    #pragma unroll
    for (int i = 0; i < 32; ++i) {
      float a = 5.f * src[(size_t)(l0 + i) * HID];
      float mn = fmaxf(m, a);
      s = s * __expf(m - mn) + __expf(a - mn);
      m = mn;
      pm[i] = m; ps[i] = s;
    }
    float cm = m, cs = s;
    #pragma unroll
    for (int off = 1; off < 64; off <<= 1) {
      float om = __shfl_up(cm, off);
      float os = __shfl_up(cs, off);
      if (lane >= off) {
        float mn = fmaxf(om, cm);
        cs = os * __expf(om - mn) + cs * __expf(cm - mn);
        cm = mn;
      }
    }
    float em = __shfl_up(cm, 1);
    float es = __shfl_up(cs, 1);
    if (lane == 0) { em = -INFINITY; es = 0.f; }
    #pragma unroll
    for (int i = 0; i < 32; ++i) {
      float mn = fmaxf(em, pm[i]);
      float S = es * __expf(em - mn) + ps[i] * __expf(pm[i] - mn);
      float v = (mn + logf(S)) * 0.2f;
      xt[((size_t)b * LSEQ + l0 + i) * HID + 320 + c] = (_Float16)v;
    }
  } else {
    int gid = (blockIdx.x - 32) * 256 + threadIdx.x;
    int c = 384 + (gid & 127);
    size_t tok = (size_t)(gid >> 7);
    int l = (int)(tok & (LSEQ - 1));
    float v;
    if (c < 448) v = (l >= 1) ? xn[(tok - 1) * HID + c] : 0.f;
    else         v = (l >= 2) ? xn[(tok - 2) * HID + c] : 0.f;
    xt[tok * HID + c] = (_Float16)v;
  }
}

// ---------------- proj GEMM: 256x128 tile, 512 threads, XCD swizzle,
//                  LDS-transposed coalesced stores for V (r10) AND q/k (r17) --
__global__ __launch_bounds__(512) void proj_gemm(const _Float16* __restrict__ A,
                                                 const _Float16* __restrict__ Bt,
                                                 _Float16* __restrict__ qb,
                                                 _Float16* __restrict__ kb,
                                                 _Float16* __restrict__ vT,
                                                 _Float16* __restrict__ act) {
  __shared__ __align__(16) char smem[49152];
  _Float16* AsB = (_Float16*)smem;            // 2 bufs x 8192 (32KB)
  _Float16* BsB = (_Float16*)(smem + 32768);  // 2 bufs x 4096 (16KB)
  const int tid = threadIdx.x;
  const int w = tid >> 6, lane = tid & 63;   // w in 0..7
  const int wm = w >> 1, wn = w & 1;         // 4M x 2N wave grid, 64x64 each
  const int quad = lane >> 4, li = lane & 15;
  const int bid = blockIdx.x;                // 0..447
  const int k8 = bid & 7, ci = bid >> 3;     // XCD id, chunk index 0..55
  const int bx = (k8 & 1) * 14 + (ci % 14);  // N-block 0..27
  const int by = (k8 >> 1) * 4 + (ci / 14);  // M-block 0..15
  const int M0 = by * 256, N0 = bx * 128;
  const int lr = lane >> 2;
  const int lc = (lane & 3) * 8;
  f32x4 acc[4][4] = {};
  const _Float16* Ab = A  + (size_t)(M0 + w * 32 + lr) * 512 + lc;
  const _Float16* Bb = Bt + (size_t)(N0 + w * 16 + lr) * 512 + lc;

  auto stage = [&](int buf, int k0) {
    _Float16* AsW = &AsB[buf * 8192 + (w * 32) * 32];
    _Float16* BsW = &BsB[buf * 4096 + (w * 16) * 32];
    load_lds16(Ab + k0,            AsW);
    load_lds16(Ab + 16 * 512 + k0, AsW + 16 * 32);
    load_lds16(Bb + k0,            BsW);
  };

  stage(0, 0);
  __syncthreads();
  int cur = 0;
  for (int t = 0; t < 16; ++t) {
    if (t < 15) stage(cur ^ 1, (t + 1) * 32);
    h8_t af[4], bf[4];
    #pragma unroll
    for (int i = 0; i < 4; ++i) {
      af[i] = *(const h8_t*)&AsB[cur * 8192 + (wm * 64 + i * 16 + li) * 32 + quad * 8];
      bf[i] = *(const h8_t*)&BsB[cur * 4096 + (wn * 64 + i * 16 + li) * 32 + quad * 8];
    }
    #pragma unroll
    for (int mi = 0; mi < 4; ++mi)
      #pragma unroll
      for (int ni = 0; ni < 4; ++ni)
        acc[mi][ni] = __builtin_amdgcn_mfma_f32_16x16x32_f16(af[mi], bf[ni], acc[mi][ni], 0, 0, 0);
    __syncthreads();
    cur ^= 1;
  }

  if (N0 < 1024) {
    // ---- q/k block: LDS roundtrip -> coalesced 64B-run stores (r17) ----
    _Float16* T = (_Float16*)smem;            // 128 x 136 x 2B = 34.8KB
    const int b = M0 >> 11;
    const bool isK = (N0 >= 512);
    const int hbase = (isK ? (N0 - 512) : N0) >> 6;
    _Float16* dstb = isK ? kb : qb;
    const int lrow = tid >> 2, seg = tid & 3;
    #pragma unroll
    for (int c = 0; c < 2; ++c) {
      __syncthreads();
      if ((wm >> 1) == c) {
        const int lbase = (wm & 1) * 64;
        #pragma unroll
        for (int mi = 0; mi < 4; ++mi)
          #pragma unroll
          for (int ni = 0; ni < 4; ++ni)
            #pragma unroll
            for (int r = 0; r < 4; ++r)
              T[(lbase + mi * 16 + quad * 4 + r) * 136 + wn * 64 + ni * 16 + li] =
                  (_Float16)acc[mi][ni][r];
      }
      __syncthreads();
      const int l = (M0 & (LSEQ - 1)) + c * 128 + lrow;
      const int h = hbase + (seg >> 1);
      const h8_t* src = (const h8_t*)&T[lrow * 136 + seg * 32];
      h8_t* d8 = (h8_t*)&dstb[(((size_t)b * NH + h) * LSEQ + l) * HD + (seg & 1) * 32];
      d8[0] = src[0];
      d8[1] = src[1];
      d8[2] = src[2];
      d8[3] = src[3];
    }
  } else if (N0 < 1536) {
    // ---- V-block: LDS transpose -> coalesced vT stores (r10) ----
    _Float16* T = (_Float16*)smem;           // 128 l x 132-stride d tile (33.8KB)
    const int b = M0 >> 11;
    const int dloc = tid >> 2, l0 = (tid & 3) * 32;
    const int h = ((N0 - 1024) >> 6) + (dloc >> 6);
    const int dd = dloc & 63;
    #pragma unroll
    for (int c = 0; c < 2; ++c) {
      __syncthreads();
      if ((wm >> 1) == c) {
        const int lbase = (wm & 1) * 64;
        #pragma unroll
        for (int mi = 0; mi < 4; ++mi)
          #pragma unroll
          for (int ni = 0; ni < 4; ++ni)
            #pragma unroll
            for (int r = 0; r < 4; ++r)
              T[(lbase + mi * 16 + quad * 4 + r) * 132 + wn * 64 + ni * 16 + li] =
                  (_Float16)acc[mi][ni][r];
      }
      __syncthreads();
      _Float16* dstrow = vT + (((size_t)b * NH + h) * HD + dd) * LSEQ
                            + (M0 & (LSEQ - 1)) + c * 128;
      #pragma unroll
      for (int i = 0; i < 4; ++i) {
        h8_t v8;
        #pragma unroll
        for (int e = 0; e < 8; ++e) v8[e] = T[(l0 + i * 8 + e) * 132 + dloc];
        *(h8_t*)&dstrow[l0 + i * 8] = v8;
      }
    }
  } else {
    #pragma unroll
    for (int mi = 0; mi < 4; ++mi)
      #pragma unroll
      for (int ni = 0; ni < 4; ++ni)
        #pragma unroll
        for (int r = 0; r < 4; ++r) {
          int mrow = M0 + wm * 64 + mi * 16 + quad * 4 + r;
          int n = N0 + wn * 64 + ni * 16 + li;
          float v = acc[mi][ni][r];
          float g = 0.5f * v * (1.f + erff(v * 0.70710678f));
          act[(size_t)mrow * VPN + 512 + (n - 1536)] = (_Float16)g;
        }
  }
}

// ---------------- flash attention, split-K=2 + ALiBi window + XCD pairing
//                  + 8 waves/block + reg-prefetch w/ lgkm-only barriers (r19) -
// r13's mechanism retried with its masking cost removed: at the 8-wave base
// (VGPR 64), prefetch regs cost +16 VGPR -> ~80, no occupancy change (grid-
// bound 2 blocks/CU; LDS would allow 3). K/V loads for tile t+1 issue right
// after tile t's staging barrier and fly under QK+softmax+PV; all in-loop
// barriers are lgkm-only so the loads stay in flight. Ledger as r13:
// (B) staging ds_writes drained+barrier; (C) K reads drained before P
// overwrite; (A') Vt/P reads drained before next iteration's ds_write.
__global__ __launch_bounds__(512) void attn_partial(const _Float16* __restrict__ qb,
                                                    const _Float16* __restrict__ kb,
                                                    const _Float16* __restrict__ vTb,
                                                    _Float16* __restrict__ Opart,
                                                    float* __restrict__ zpart) {
  __shared__ __align__(16) _Float16 KtP[128 * 136];
  __shared__ __align__(16) _Float16 Vt[64 * 136];
  const int bid = blockIdx.x;                 // 0..511
  const int k8 = bid & 7, ci = bid >> 3;      // ci 0..63
  const int half = ci >> 5;
  const int hh = k8 & 3;
  const int bh = ((k8 & 4) << 1) + (half ? 7 - hh : hh);  // {h,7-h} pairing
  const int rr_ = ci & 31;
  const int qt = 15 - (rr_ >> 1);             // heavy-first (LPT)
  const int s = rr_ & 1;
  const int tid = threadIdx.x;
  const int w = tid >> 6, lane = tid & 63;    // w in 0..7
  const int quad = lane >> 4, li = lane & 15;
  const int h = bh & 7;
  const float LOG2E = 1.44269504f;
  const float slope2 = exp2f(-(float)(h + 1)) * LOG2E;
  const float SCALE2 = 0.125f * LOG2E;
  const _Float16* qp = qb + (size_t)bh * LSEQ * HD;
  const _Float16* kp = kb + (size_t)bh * LSEQ * HD;
  const _Float16* vp = vTb + (size_t)bh * HD * LSEQ;
  const int q0 = qt * 128;
  const int qlb = w * 16;                     // 16 q-rows per wave

  const int wint = (int)(48.0f / slope2);
  const int lo = q0 - wint;
  int jt_min = lo > 0 ? lo / 128 : 0;
  int d2 = ((s - jt_min) % 2 + 2) % 2;
  const int jt0 = jt_min + d2;

  h8_t qf[2];
  #pragma unroll
  for (int kk = 0; kk < 2; ++kk)
    qf[kk] = *(const h8_t*)&qp[(size_t)(q0 + qlb + li) * HD + kk * 32 + quad * 8];

  f32x4 oacc[4] = {};
  float mrow[4], lrow[4];
  #pragma unroll
  for (int r = 0; r < 4; ++r) { mrow[r] = -INFINITY; lrow[r] = 0.f; }

  const int rr = tid >> 3, ss = (tid & 7) * 8;      // K: 64 rows x 64 cols / pass
  const int dd = tid >> 4, s2 = (tid & 15) * 8;     // V: 32 rows x 128 cols / pass

  // prefetch registers (thread-private)
  h8_t kreg[2], vreg[2];
  auto issue = [&](int j0) {
    #pragma unroll
    for (int i = 0; i < 2; ++i) {
      kreg[i] = *(const h8_t*)&kp[(size_t)(j0 + rr + i * 64) * HD + ss];
      vreg[i] = *(const h8_t*)&vp[(size_t)(dd + i * 32) * LSEQ + j0 + s2];
    }
  };

  if (jt0 <= qt) issue(jt0 * 128);

  for (int jt = jt0; jt <= qt; jt += 2) {
    const int j0 = jt * 128;
    // write prefetched regs -> LDS (compiler inserts vmcnt wait on use)
    #pragma unroll
    for (int i = 0; i < 2; ++i) {
      *(h8_t*)&KtP[(rr + i * 64) * 72 + ss] = kreg[i];
      *(h8_t*)&Vt[(dd + i * 32) * 136 + s2] = vreg[i];
    }
    BARRIER_LG;                          // (B) staging visible to all waves
    if (jt + 2 <= qt) issue(j0 + 256);   // next tile's loads fly under compute

    f32x4 sc[8] = {};
    #pragma unroll
    for (int jn = 0; jn < 8; ++jn) {
      h8_t b0 = *(const h8_t*)&KtP[(jn * 16 + li) * 72 + quad * 8];
      h8_t b1 = *(const h8_t*)&KtP[(jn * 16 + li) * 72 + 32 + quad * 8];
      sc[jn] = __builtin_amdgcn_mfma_f32_16x16x32_f16(qf[0], b0, sc[jn], 0, 0, 0);
      sc[jn] = __builtin_amdgcn_mfma_f32_16x16x32_f16(qf[1], b1, sc[jn], 0, 0, 0);
    }
    const bool diag = (jt == qt);
    float rmax[4];
    #pragma unroll
    for (int r = 0; r < 4; ++r) rmax[r] = -INFINITY;
    #pragma unroll
    for (int jn = 0; jn < 8; ++jn)
      #pragma unroll
      for (int r = 0; r < 4; ++r) {
        int j = j0 + jn * 16 + li;
        float v = sc[jn][r] * SCALE2 + slope2 * (float)j;
        if (diag && j > q0 + qlb + quad * 4 + r) v = -1e30f;
        sc[jn][r] = v;
        rmax[r] = fmaxf(rmax[r], v);
      }
    #pragma unroll
    for (int r = 0; r < 4; ++r) {
      float v = rmax[r];
      v = fmaxf(v, __shfl_xor(v, 1));
      v = fmaxf(v, __shfl_xor(v, 2));
      v = fmaxf(v, __shfl_xor(v, 4));
      v = fmaxf(v, __shfl_xor(v, 8));
      rmax[r] = v;
    }
    float alpha[4];
    #pragma unroll
    for (int r = 0; r < 4; ++r) {
      float mn = fmaxf(mrow[r], rmax[r]);
      alpha[r] = exp2f(mrow[r] - mn);
      mrow[r] = mn;
    }
    float rsum[4] = {};
    #pragma unroll
    for (int jn = 0; jn < 8; ++jn)
      #pragma unroll
      for (int r = 0; r < 4; ++r) {
        float p = exp2f(sc[jn][r] - mrow[r]);
        sc[jn][r] = p;
        rsum[r] += p;
      }
    #pragma unroll
    for (int r = 0; r < 4; ++r) {
      float v = rsum[r];
      v += __shfl_xor(v, 1);
      v += __shfl_xor(v, 2);
      v += __shfl_xor(v, 4);
      v += __shfl_xor(v, 8);
      lrow[r] = lrow[r] * alpha[r] + v;
    }
    #pragma unroll
    for (int nd = 0; nd < 4; ++nd)
      #pragma unroll
      for (int r = 0; r < 4; ++r) oacc[nd][r] *= alpha[r];

    BARRIER_LG;                          // (C) all K reads drained before P overwrite
    #pragma unroll
    for (int jn = 0; jn < 8; ++jn)
      #pragma unroll
      for (int r = 0; r < 4; ++r)
        KtP[(qlb + quad * 4 + r) * 136 + jn * 16 + li] = (_Float16)sc[jn][r];
    #pragma unroll
    for (int kk = 0; kk < 4; ++kk) {
      h8_t pf = *(const h8_t*)&KtP[(qlb + li) * 136 + kk * 32 + quad * 8];
      #pragma unroll
      for (int nd = 0; nd < 4; ++nd) {
        h8_t vf = *(const h8_t*)&Vt[(nd * 16 + li) * 136 + kk * 32 + quad * 8];
        oacc[nd] = __builtin_amdgcn_mfma_f32_16x16x32_f16(pf, vf, oacc[nd], 0, 0, 0);
      }
    }
    BARRIER_LG;                          // (A') all Vt/P reads drained before next ds_write
  }

  const size_t pbase = ((size_t)bh * 16 + qt) * 2 + s;
  #pragma unroll
  for (int r = 0; r < 4; ++r) {
    int prow = qlb + quad * 4 + r;
    float l = lrow[r];
    float inv = (l > 0.f) ? 1.f / l : 0.f;
    if (li == 0)
      zpart[pbase * 128 + prow] = (l > 0.f) ? mrow[r] + log2f(l) : -INFINITY;  // base-2 z
    #pragma unroll
    for (int nd = 0; nd < 4; ++nd)
      Opart[pbase * 8192 + (size_t)prow * 64 + nd * 16 + li] =
          (_Float16)(oacc[nd][r] * inv);
  }
}

// ---------------- attention combine (split-2, z is base-2) ----------------
__global__ __launch_bounds__(256) void attn_combine(const _Float16* __restrict__ Opart,
                                                    const float* __restrict__ zpart,
                                                    _Float16* __restrict__ act) {
  int g = blockIdx.x * 64 + (threadIdx.x >> 2);
  int c0 = (threadIdx.x & 3) * 16;
  int bh = g >> 11, l = g & 2047;
  int qt = l >> 7, row = l & 127;
  size_t pbase = ((size_t)bh * 16 + qt) * 2;
  float z[2], wgt[2];
  float Z = -INFINITY;
  #pragma unroll
  for (int s = 0; s < 2; ++s) {
    z[s] = zpart[(pbase + s) * 128 + row];
    Z = fmaxf(Z, z[s]);
  }
  float W = 0.f;
  #pragma unroll
  for (int s = 0; s < 2; ++s) { wgt[s] = exp2f(z[s] - Z); W += wgt[s]; }
  float inv = 1.f / W;
  float acc[16] = {};
  #pragma unroll
  for (int s = 0; s < 2; ++s) {
    const h8_t* p = (const h8_t*)&Opart[(pbase + s) * 8192 + (size_t)row * 64 + c0];
    h8_t a = p[0], b = p[1];
    #pragma unroll
    for (int i = 0; i < 8; ++i) {
      acc[i] += wgt[s] * (float)a[i];
      acc[8 + i] += wgt[s] * (float)b[i];
    }
  }
  int b_ = bh >> 3, h = bh & 7;
  _Float16* dst = &act[((size_t)b_ * LSEQ + l) * VPN + h * 64 + c0];
  h8_t o0, o1;
  #pragma unroll
  for (int i = 0; i < 8; ++i) {
    o0[i] = (_Float16)(acc[i] * inv);
    o1[i] = (_Float16)(acc[8 + i] * inv);
  }
  ((h8_t*)dst)[0] = o0;
  ((h8_t*)dst)[1] = o1;
}

// ---------------- out GEMM, split-K=4, 3-buffer ring + XCD-chunked swizzle ----
__global__ __launch_bounds__(256) void out_gemm_sk(const _Float16* __restrict__ A,
                                                   const _Float16* __restrict__ Bt,
                                                   float* __restrict__ part0,
                                                   float* __restrict__ part1,
                                                   float* __restrict__ part2,
                                                   float* __restrict__ part3) {
  __shared__ __align__(16) _Float16 As[3][128 * 32];
  __shared__ __align__(16) _Float16 Bs[3][128 * 32];
  const int tid = threadIdx.x;
  const int w = tid >> 6, lane = tid & 63;
  const int wm = w >> 1, wn = w & 1;
  const int quad = lane >> 4, li = lane & 15;
  const int bid = blockIdx.x;               // 0..511
  const int k8 = bid & 7, ci = bid >> 3;    // ci 0..63
  const int sk = k8 >> 1;                   // 0..3
  const int bx = ci & 3;                    // 0..3
  const int by = (k8 & 1) * 16 + (ci >> 2); // 0..31
  const int M0 = by * 128, N0 = bx * 128;
  const int lr = lane >> 2;
  const int lc = (lane & 3) * 8;
  f32x4 acc[4][4] = {};
  const _Float16* Ab = A  + (size_t)(M0 + w * 32 + lr) * 2560 + lc;
  const _Float16* Bb = Bt + (size_t)(N0 + w * 32 + lr) * 2560 + lc;
  const int kbeg = sk * 640;

  auto stage = [&](int buf, int t) {
    const int k0 = kbeg + t * 32;
    _Float16* AsW = &As[buf][(w * 32) * 32];
    _Float16* BsW = &Bs[buf][(w * 32) * 32];
    load_lds16(Ab + k0,             AsW);
    load_lds16(Ab + 16 * 2560 + k0, AsW + 16 * 32);
    load_lds16(Bb + k0,             BsW);
    load_lds16(Bb + 16 * 2560 + k0, BsW + 16 * 32);
  };

  stage(0, 0);
  stage(1, 1);
  WAITBAR(4);
  #pragma unroll
  for (int t = 0; t < 20; ++t) {
    const int cur = t % 3;
    if (t + 2 < 20) stage((t + 2) % 3, t + 2);
    h8_t af[4], bf[4];
    #pragma unroll
    for (int i = 0; i < 4; ++i) {
      af[i] = *(const h8_t*)&As[cur][(wm * 64 + i * 16 + li) * 32 + quad * 8];
      bf[i] = *(const h8_t*)&Bs[cur][(wn * 64 + i * 16 + li) * 32 + quad * 8];
    }
    #pragma unroll
    for (int mi = 0; mi < 4; ++mi)
      #pragma unroll
      for (int ni = 0; ni < 4; ++ni)
        acc[mi][ni] = __builtin_amdgcn_mfma_f32_16x16x32_f16(af[mi], bf[ni], acc[mi][ni], 0, 0, 0);
    if (t < 19) {
      if (t + 2 < 20) WAITBAR(4);
      else            WAITBAR(0);
    }
  }
  float* dst = (sk == 0) ? part0 : (sk == 1) ? part1 : (sk == 2) ? part2 : part3;
  #pragma unroll
  for (int mi = 0; mi < 4; ++mi)
    #pragma unroll
    for (int ni = 0; ni < 4; ++ni)
      #pragma unroll
      for (int r = 0; r < 4; ++r) {
        int m = M0 + wm * 64 + mi * 16 + quad * 4 + r;
        int n = N0 + wn * 64 + ni * 16 + li;
        dst[(size_t)m * HID + n] = acc[mi][ni][r];
      }
}

// ---------------- combine split-K partials + bias ----------------
__global__ __launch_bounds__(256) void out_combine(const float* __restrict__ part0,
                                                   const float* __restrict__ part1,
                                                   const float* __restrict__ part2,
                                                   const float* __restrict__ part3,
                                                   const float* __restrict__ bias,
                                                   float* __restrict__ out) {
  int idx = (blockIdx.x * 256 + threadIdx.x) * 4;
  float4 a = *(const float4*)&part0[idx];
  float4 b = *(const float4*)&part1[idx];
  float4 c = *(const float4*)&part2[idx];
  float4 d = *(const float4*)&part3[idx];
  float4 e = *(const float4*)&bias[idx & 511];
  float4 o;
  o.x = a.x + b.x + c.x + d.x + e.x;
  o.y = a.y + b.y + c.y + d.y + e.y;
  o.z = a.z + b.z + c.z + d.z + e.z;
  o.w = a.w + b.w + c.w + d.w + e.w;
  *(float4*)&out[idx] = o;
}

extern "C" void kernel_launch(void* const* d_in, const int* in_sizes, int n_in,
                              void* d_out, int out_size, void* d_ws, size_t ws_size,
                              hipStream_t stream) {
  const float* x      = (const float*)d_in[0];
  const float* gamma  = (const float*)d_in[1];
  const float* beta   = (const float*)d_in[2];
  const float* w_in   = (const float*)d_in[3];
  const float* w_out  = (const float*)d_in[4];
  const float* b_out  = (const float*)d_in[5];
  float* out = (float*)d_out;
  char* ws = (char*)d_ws;

  float*    xn     = (float*)(ws);                    // 8,388,608 B
  _Float16* xt     = (_Float16*)(ws + 8388608);       // 4,194,304 B
  _Float16* w_inT  = (_Float16*)(ws + 12582912);      // 3,670,016 B
  _Float16* w_outT = (_Float16*)(ws + 16252928);      // 2,621,440 B
  _Float16* qb     = (_Float16*)(ws + 18874368);      // 4,194,304 B
  _Float16* kb     = (_Float16*)(ws + 23068672);      // 4,194,304 B
  _Float16* vT     = (_Float16*)(ws + 27262976);      // 4,194,304 B
  _Float16* act    = (_Float16*)(ws + 31457280);      // 20,971,520 B
  _Float16* Opart  = (_Float16*)(ws + 52428800);      // 8,388,608 B used (split-2)
  float*    zpart  = (float*)(ws + 69206016);         // 262,144 B used
  float*    opart_0 = (float*)(ws);
  float*    opart_1 = (float*)(ws + 18874368);
  float*    opart_2 = (float*)(ws + 52428800);
  float*    opart_3 = (float*)(ws + 60817408);

  prep_kernel<<<dim3(TOK + 1792 + 1280), 256, 0, stream>>>(x, gamma, beta, w_in, w_out,
                                                           xn, xt, w_inT, w_outT);
  xt_scan_shift<<<dim3(32 + TOK * 128 / 256), 256, 0, stream>>>(xn, xt);
  proj_gemm<<<dim3(448), 512, 0, stream>>>(xt, w_inT, qb, kb, vT, act);
  attn_partial<<<dim3(512), 512, 0, stream>>>(qb, kb, vT, Opart, zpart);
  attn_combine<<<dim3(16 * LSEQ / 64), 256, 0, stream>>>(Opart, zpart, act);
  out_gemm_sk<<<dim3(512), 256, 0, stream>>>(act, w_outT,
                                             opart_0, opart_1, opart_2, opart_3);
  out_combine<<<dim3(TOK * HID / 4 / 256), 256, 0, stream>>>(opart_0, opart_1, opart_2, opart_3,
                                                             b_out, out);
}